// Round 13
// baseline (856.019 us; speedup 1.0000x reference)
//
#include <hip/hip_runtime.h>
#include <hip/hip_bf16.h>

typedef __hip_bfloat16 bf16;
typedef __attribute__((ext_vector_type(8))) unsigned short ushort8v;
typedef __bf16 bf16x8 __attribute__((ext_vector_type(8)));
typedef float f32x4 __attribute__((ext_vector_type(4)));

#define NTOK 4096
#define DMODEL 1024
#define NHEADS 16
#define HD 64
#define DC 128
#define DFF2 4096
#define NEXP 8
#define LSEQ 1024
#define NBATCH 4
#define RMS_EPS 1.1920928955078125e-07f
#define WSCALE 32.0f
#define WISCALE 0.03125f

union U8 { ushort8v u; bf16x8 b; };

__device__ __forceinline__ float bf2f(unsigned short u) {
  return __uint_as_float(((unsigned int)u) << 16);
}
__device__ __forceinline__ unsigned short f2bf(float f) {
  unsigned int u = __float_as_uint(f);
  unsigned int r = (u + 0x7FFF + ((u >> 16) & 1)) >> 16;
  return (unsigned short)r;
}
// OCP e4m3 encode, RNE, saturate-to-448 (no inf; only S.1111.111 is NaN)
__device__ __forceinline__ unsigned char f2fp8(float f) {
  unsigned int u = __float_as_uint(f);
  unsigned int s = (u >> 24) & 0x80u;
  float a = fabsf(f);
  if (!(a < 448.f)) a = 448.f;
  if (a < 0.015625f) {  // subnormal: ulp 2^-9 (m==8 falls through to 0x08 = 2^-6)
    int m = (int)rintf(a * 512.f);
    return (unsigned char)(s | (unsigned)m);
  }
  unsigned int b = __float_as_uint(a);
  b += 0x000FFFFFu + ((b >> 20) & 1u);
  int e = (int)((b >> 23) & 0xFF) - 127;
  if (e > 8) return (unsigned char)(s | 0x7E);
  unsigned int code = s | ((unsigned int)(e + 7) << 3) | ((b >> 20) & 7u);
  if ((code & 0x7F) > 0x7E) code = s | 0x7E;
  return (unsigned char)code;
}
__device__ __forceinline__ void gload_lds16(const unsigned short* g, unsigned short* l) {
  __builtin_amdgcn_global_load_lds(
      (__attribute__((address_space(1))) void*)(const_cast<unsigned short*>(g)),
      (__attribute__((address_space(3))) void*)(l), 16, 0, 0);
}
__device__ __forceinline__ void gload_lds16b(const unsigned char* g, unsigned char* l) {
  __builtin_amdgcn_global_load_lds(
      (__attribute__((address_space(1))) void*)(const_cast<unsigned char*>(g)),
      (__attribute__((address_space(3))) void*)(l), 16, 0, 0);
}

// ---------------------------------------------------------------- rmsnorm (optional bf16 and/or fp8 outputs)
__global__ __launch_bounds__(256)
void rmsnorm_kernel(const float* __restrict__ x, const float* __restrict__ w,
                    float* __restrict__ o, unsigned short* __restrict__ ob,
                    unsigned char* __restrict__ o8) {
  int t = blockIdx.x;
  int tid = threadIdx.x;
  const float4* xr = (const float4*)(x + (size_t)t * DMODEL);
  float4 v = xr[tid];
  float ss = v.x * v.x + v.y * v.y + v.z * v.z + v.w * v.w;
#pragma unroll
  for (int off = 32; off > 0; off >>= 1) ss += __shfl_xor(ss, off);
  __shared__ float red[4];
  int wid = tid >> 6, lane = tid & 63;
  if (lane == 0) red[wid] = ss;
  __syncthreads();
  float tot = red[0] + red[1] + red[2] + red[3];
  float scale = rsqrtf(tot * (1.0f / DMODEL) + RMS_EPS);
  float4 wv = ((const float4*)w)[tid];
  float4 ov;
  ov.x = v.x * scale * wv.x;
  ov.y = v.y * scale * wv.y;
  ov.z = v.z * scale * wv.z;
  ov.w = v.w * scale * wv.w;
  if (o) ((float4*)(o + (size_t)t * DMODEL))[tid] = ov;
  if (ob) {
    unsigned short* orow = ob + (size_t)t * DMODEL + tid * 4;
    orow[0] = f2bf(ov.x); orow[1] = f2bf(ov.y);
    orow[2] = f2bf(ov.z); orow[3] = f2bf(ov.w);
  }
  if (o8) {
    uchar4 q;
    q.x = f2fp8(ov.x); q.y = f2fp8(ov.y);
    q.z = f2fp8(ov.z); q.w = f2fp8(ov.w);
    *(uchar4*)(o8 + (size_t)t * DMODEL + tid * 4) = q;
  }
}

// ---------------------------------------------------------------- f32 -> bf16 conversion (single src)
__global__ __launch_bounds__(256)
void cvt_bf16_kernel(const float* __restrict__ in, unsigned short* __restrict__ o, int n8) {
  int stride = gridDim.x * 256;
  for (int i = blockIdx.x * 256 + threadIdx.x; i < n8; i += stride) {
    float4 a = ((const float4*)in)[2 * i];
    float4 b = ((const float4*)in)[2 * i + 1];
    ushort8v u;
    u[0] = f2bf(a.x); u[1] = f2bf(a.y); u[2] = f2bf(a.z); u[3] = f2bf(a.w);
    u[4] = f2bf(b.x); u[5] = f2bf(b.y); u[6] = f2bf(b.z); u[7] = f2bf(b.w);
    *(ushort8v*)(o + (size_t)i * 8) = u;
  }
}

// ---------------------------------------------------------------- f32 -> fp8 (x WSCALE) weight conversion
__global__ __launch_bounds__(256)
void cvt_fp8_kernel(const float* __restrict__ in, unsigned char* __restrict__ o, int n8) {
  int stride = gridDim.x * 256;
  for (int i = blockIdx.x * 256 + threadIdx.x; i < n8; i += stride) {
    float4 a = ((const float4*)in)[2 * i];
    float4 b = ((const float4*)in)[2 * i + 1];
    unsigned char q[8];
    q[0] = f2fp8(WSCALE * a.x); q[1] = f2fp8(WSCALE * a.y);
    q[2] = f2fp8(WSCALE * a.z); q[3] = f2fp8(WSCALE * a.w);
    q[4] = f2fp8(WSCALE * b.x); q[5] = f2fp8(WSCALE * b.y);
    q[6] = f2fp8(WSCALE * b.z); q[7] = f2fp8(WSCALE * b.w);
    *(unsigned long*)(o + (size_t)i * 8) = *(const unsigned long*)q;
  }
}

// ---------------------------------------------------------------- segmented f32 -> bf16 (up to 3 srcs, concat dst)
__global__ __launch_bounds__(256)
void cvt3_bf16_kernel(const float* __restrict__ s0, int n0,
                      const float* __restrict__ s1, int n1,
                      const float* __restrict__ s2, int n2,
                      unsigned short* __restrict__ o) {
  int total = n0 + n1 + n2;
  int stride = gridDim.x * 256;
  for (int i = blockIdx.x * 256 + threadIdx.x; i < total; i += stride) {
    const float* src;
    int li = i;
    if (li < n0) src = s0;
    else if ((li -= n0) < n1) src = s1;
    else { li -= n1; src = s2; }
    float4 a = ((const float4*)src)[2 * li];
    float4 b = ((const float4*)src)[2 * li + 1];
    ushort8v u;
    u[0] = f2bf(a.x); u[1] = f2bf(a.y); u[2] = f2bf(a.z); u[3] = f2bf(a.w);
    u[4] = f2bf(b.x); u[5] = f2bf(b.y); u[6] = f2bf(b.z); u[7] = f2bf(b.w);
    *(ushort8v*)(o + (size_t)i * 8) = u;
  }
}

// ---------------------------------------------------------------- dense bf16 MFMA GEMM (m97 structure, 128x128), + addend
__global__ __launch_bounds__(256)
void gemm_bf16(const unsigned short* __restrict__ Ab, const unsigned short* __restrict__ Wb,
               float* __restrict__ Cf, const float* __restrict__ addend, int N, int K) {
  __shared__ __align__(16) unsigned short As[128 * 64];
  __shared__ __align__(16) unsigned short Bs[128 * 64];
  int row0 = blockIdx.y * 128;
  int col0 = blockIdx.x * 128;
  int tid = threadIdx.x;
  int w = tid >> 6, l = tid & 63;
  int lr = l >> 3;
  int lc = (l & 7) * 8;

  const unsigned short* aSrc[4];
  const unsigned short* bSrc[4];
#pragma unroll
  for (int i = 0; i < 4; ++i) {
    aSrc[i] = Ab + (size_t)(row0 + i * 32 + w * 8 + lr) * K + lc;
    bSrc[i] = Wb + (size_t)(col0 + i * 32 + w * 8 + lr) * K + lc;
  }

  f32x4 acc[4][4] = {};
  int wr = w >> 1, wc = w & 1;
  int ln = l & 15, lq = l >> 4;

  for (int k0 = 0; k0 < K; k0 += 64) {
#pragma unroll
    for (int i = 0; i < 4; ++i) {
      gload_lds16(aSrc[i] + k0, &As[(i * 4 + w) * 512]);
      gload_lds16(bSrc[i] + k0, &Bs[(i * 4 + w) * 512]);
    }
    __syncthreads();
#pragma unroll
    for (int kk = 0; kk < 2; ++kk) {
      bf16x8 af[4], bfr[4];
#pragma unroll
      for (int m = 0; m < 4; ++m)
        af[m] = *(const bf16x8*)&As[(wr * 64 + m * 16 + ln) * 64 + kk * 32 + lq * 8];
#pragma unroll
      for (int n = 0; n < 4; ++n)
        bfr[n] = *(const bf16x8*)&Bs[(wc * 64 + n * 16 + ln) * 64 + kk * 32 + lq * 8];
#pragma unroll
      for (int m = 0; m < 4; ++m)
#pragma unroll
        for (int n = 0; n < 4; ++n)
          acc[m][n] = __builtin_amdgcn_mfma_f32_16x16x32_bf16(af[m], bfr[n], acc[m][n], 0, 0, 0);
    }
    __syncthreads();
  }

#pragma unroll
  for (int m = 0; m < 4; ++m) {
#pragma unroll
    for (int j = 0; j < 4; ++j) {
      int row = row0 + wr * 64 + m * 16 + lq * 4 + j;
      float* crow = Cf + (size_t)row * N + col0 + wc * 64 + ln;
      const float* arow = addend ? addend + (size_t)row * N + col0 + wc * 64 + ln : nullptr;
#pragma unroll
      for (int n = 0; n < 4; ++n) {
        float vv = acc[m][n][j];
        if (addend) vv += arow[n * 16];
        crow[n * 16] = vv;
      }
    }
  }
}

// ---------------------------------------------------------------- merged-projection GEMM (3-way dest epilogue)
__global__ __launch_bounds__(256)
void gemm_proj(const unsigned short* __restrict__ Ab, const unsigned short* __restrict__ Wcat,
               float* __restrict__ d0, float* __restrict__ d1, float* __restrict__ d2,
               unsigned short* __restrict__ d1b,
               int c1, int c2, int s0, int s1, int s2, int K) {
  __shared__ __align__(16) unsigned short As[128 * 64];
  __shared__ __align__(16) unsigned short Bs[128 * 64];
  int row0 = blockIdx.y * 128;
  int col0 = blockIdx.x * 128;
  int tid = threadIdx.x;
  int w = tid >> 6, l = tid & 63;
  int lr = l >> 3;
  int lc = (l & 7) * 8;

  const unsigned short* aSrc[4];
  const unsigned short* bSrc[4];
#pragma unroll
  for (int i = 0; i < 4; ++i) {
    aSrc[i] = Ab + (size_t)(row0 + i * 32 + w * 8 + lr) * K + lc;
    bSrc[i] = Wcat + (size_t)(col0 + i * 32 + w * 8 + lr) * K + lc;
  }

  f32x4 acc[4][4] = {};
  int wr = w >> 1, wc = w & 1;
  int ln = l & 15, lq = l >> 4;

  for (int k0 = 0; k0 < K; k0 += 64) {
#pragma unroll
    for (int i = 0; i < 4; ++i) {
      gload_lds16(aSrc[i] + k0, &As[(i * 4 + w) * 512]);
      gload_lds16(bSrc[i] + k0, &Bs[(i * 4 + w) * 512]);
    }
    __syncthreads();
#pragma unroll
    for (int kk = 0; kk < 2; ++kk) {
      bf16x8 af[4], bfr[4];
#pragma unroll
      for (int m = 0; m < 4; ++m)
        af[m] = *(const bf16x8*)&As[(wr * 64 + m * 16 + ln) * 64 + kk * 32 + lq * 8];
#pragma unroll
      for (int n = 0; n < 4; ++n)
        bfr[n] = *(const bf16x8*)&Bs[(wc * 64 + n * 16 + ln) * 64 + kk * 32 + lq * 8];
#pragma unroll
      for (int m = 0; m < 4; ++m)
#pragma unroll
        for (int n = 0; n < 4; ++n)
          acc[m][n] = __builtin_amdgcn_mfma_f32_16x16x32_bf16(af[m], bfr[n], acc[m][n], 0, 0, 0);
    }
    __syncthreads();
  }

  bool seg1 = (col0 >= c1) && (col0 < c2);
  if (seg1 && d1b) {
#pragma unroll
    for (int m = 0; m < 4; ++m) {
#pragma unroll
      for (int j = 0; j < 4; ++j) {
        int row = row0 + wr * 64 + m * 16 + lq * 4 + j;
        unsigned short* crow = d1b + (size_t)row * s1 + (col0 - c1) + wc * 64 + ln;
#pragma unroll
        for (int n = 0; n < 4; ++n) crow[n * 16] = f2bf(acc[m][n][j]);
      }
    }
    return;
  }
  float* dst;
  int cb, stride;
  if (col0 < c1) { dst = d0; cb = 0; stride = s0; }
  else if (seg1) { dst = d1; cb = c1; stride = s1; }
  else { dst = d2; cb = c2; stride = s2; }
#pragma unroll
  for (int m = 0; m < 4; ++m) {
#pragma unroll
    for (int j = 0; j < 4; ++j) {
      int row = row0 + wr * 64 + m * 16 + lq * 4 + j;
      float* crow = dst + (size_t)row * stride + (col0 - cb) + wc * 64 + ln;
#pragma unroll
      for (int n = 0; n < 4; ++n) crow[n * 16] = acc[m][n][j];
    }
  }
}

// ---------------------------------------------------------------- fp8 MFMA grouped GEMM (MoE), 128x128, R7 schedule
// N-fastest grid; operands e4m3 (weights pre-scaled x32, epilogue x1/32).
// MODE 0 (FFN1): A=hn8 gathered via tok2e>>1; silu -> fp8 hmid8.  MODE 1 (FFN2): A=hmid8; bf16 y scatter.
template <int MODE>
__global__ __launch_bounds__(256)
void moe_fp8(const unsigned char* __restrict__ A, const unsigned char* __restrict__ W8,
             unsigned char* __restrict__ C8, unsigned short* __restrict__ Cb,
             const int* __restrict__ tok2e, const int* __restrict__ ebase,
             const int* __restrict__ icnt) {
  constexpr int N = (MODE == 0) ? DFF2 : DMODEL;
  constexpr int K = (MODE == 0) ? DMODEL : DFF2;
  __shared__ __align__(16) unsigned char As[128 * 64];  // 8 KB
  __shared__ __align__(16) unsigned char Bs[128 * 64];  // 8 KB
  int e = blockIdx.z;
  int base = ebase[e];
  int cnt = icnt[e];
  int row0 = blockIdx.y * 128;
  if (row0 >= cnt) return;
  int col0 = blockIdx.x * 128;
  int tid = threadIdx.x;
  int w = tid >> 6, l = tid & 63;
  int lr = l >> 2;          // 16 rows per wave-round
  int lc = (l & 3) * 16;    // 4 x 16B chunks per 64B row

  const unsigned char* aSrc[2];
  const unsigned char* bSrc[2];
#pragma unroll
  for (int i = 0; i < 2; ++i) {
    int r = row0 + i * 64 + w * 16 + lr;
    r = r < cnt ? r : cnt - 1;
    if (MODE == 0) {
      int tok = tok2e[base + r] >> 1;
      aSrc[i] = A + (size_t)tok * K + lc;
    } else {
      aSrc[i] = A + (size_t)(base + r) * K + lc;
    }
    int nrow = col0 + i * 64 + w * 16 + lr;
    bSrc[i] = W8 + (size_t)e * N * K + (size_t)nrow * K + lc;
  }

  f32x4 acc[4][4] = {};
  int wr = w >> 1, wc = w & 1;
  int ln = l & 15, lq = l >> 4;

  for (int k0 = 0; k0 < K; k0 += 64) {
#pragma unroll
    for (int i = 0; i < 2; ++i) {
      gload_lds16b(aSrc[i] + k0, &As[(i * 64 + w * 16) * 64]);
      gload_lds16b(bSrc[i] + k0, &Bs[(i * 64 + w * 16) * 64]);
    }
    __syncthreads();
#pragma unroll
    for (int kk = 0; kk < 2; ++kk) {
      long af[4], bfr[4];
#pragma unroll
      for (int m = 0; m < 4; ++m)
        af[m] = *(const long*)&As[(wr * 64 + m * 16 + ln) * 64 + kk * 32 + lq * 8];
#pragma unroll
      for (int n = 0; n < 4; ++n)
        bfr[n] = *(const long*)&Bs[(wc * 64 + n * 16 + ln) * 64 + kk * 32 + lq * 8];
#pragma unroll
      for (int m = 0; m < 4; ++m)
#pragma unroll
        for (int n = 0; n < 4; ++n)
          acc[m][n] = __builtin_amdgcn_mfma_f32_16x16x32_fp8_fp8(af[m], bfr[n], acc[m][n], 0, 0, 0);
    }
    __syncthreads();
  }

#pragma unroll
  for (int m = 0; m < 4; ++m) {
#pragma unroll
    for (int j = 0; j < 4; ++j) {
      int r = row0 + wr * 64 + m * 16 + lq * 4 + j;
      if (r < cnt) {
        if (MODE == 0) {
          unsigned char* orow = C8 + (size_t)(base + r) * N + col0 + wc * 64 + ln;
#pragma unroll
          for (int n = 0; n < 4; ++n) {
            float v = acc[m][n][j] * WISCALE;
            float s = v / (1.f + __expf(-v));
            orow[n * 16] = f2fp8(s);
          }
        } else {
          int t2 = tok2e[base + r];
          unsigned short* orow = Cb + (size_t)t2 * N + col0 + wc * 64 + ln;
#pragma unroll
          for (int n = 0; n < 4; ++n) orow[n * 16] = f2bf(acc[m][n][j] * WISCALE);
        }
      }
    }
  }
}

// ---------------------------------------------------------------- fused rope (cos-only) + ksum + bf16 per-(b,h) relayout
__global__ __launch_bounds__(256)
void rope_qk_kernel(const float* __restrict__ q, const float* __restrict__ k,
                    const float* __restrict__ kc, const float* __restrict__ tsq,
                    const float* __restrict__ tskv,
                    unsigned short* __restrict__ Qb, unsigned short* __restrict__ Kb) {
  int t = blockIdx.x;
  int tid = threadIdx.x;
  __shared__ float cq[32], ck[32];
  if (tid < 32) {
    float fr = __expf(-(float)(2 * tid) * (1.0f / HD) * 9.210340371976184f);  // ln(10000)
    cq[tid] = cosf(tsq[t] * fr);
    ck[tid] = cosf(tskv[t] * fr);
  }
  __syncthreads();
  int b = t >> 10, lrow = t & 1023;
  size_t rb = (size_t)t * DMODEL;
  for (int p = tid; p < 512; p += 256) {
    int hh = p >> 5, d = p & 31;
    int c1 = hh * 64 + d, c2 = c1 + 32;
    float cqd = cq[d], ckd = ck[d];
    float q1 = q[rb + c1], q2 = q[rb + c2];
    float rq1 = (q1 * cqd - q2 * ckd) * 0.125f;
    float rq2 = (q2 * cqd + q1 * ckd) * 0.125f;
    float k1 = k[rb + c1], k2 = k[rb + c2];
    float rk1 = (k1 * cqd - k2 * ckd) + kc[rb + c1];
    float rk2 = (k2 * cqd + k1 * ckd) + kc[rb + c2];
    size_t dst = ((size_t)(b * NHEADS + hh) * LSEQ + lrow) * HD;
    Qb[dst + d] = f2bf(rq1);
    Qb[dst + d + 32] = f2bf(rq2);
    Kb[dst + d] = f2bf(rk1);
    Kb[dst + d + 32] = f2bf(rk2);
  }
}

// ---------------------------------------------------------------- v transpose (bf16 in, bf16 out)  [bh][64][1024]
__global__ __launch_bounds__(256)
void v_split_kernel(const unsigned short* __restrict__ vbb, unsigned short* __restrict__ Vt) {
  __shared__ unsigned short tile[128][72];
  int bh = blockIdx.x;
  int lt = blockIdx.y;
  int b = bh >> 4, hh = bh & 15;
  int tid = threadIdx.x;
#pragma unroll
  for (int pass = 0; pass < 8; ++pass) {
    int r = pass * 16 + (tid >> 4);
    int dq = (tid & 15) * 4;
    ushort4 vv = *(const ushort4*)(vbb + (size_t)(b * 1024 + lt * 128 + r) * DMODEL + hh * 64 + dq);
    tile[r][dq + 0] = vv.x; tile[r][dq + 1] = vv.y;
    tile[r][dq + 2] = vv.z; tile[r][dq + 3] = vv.w;
  }
  __syncthreads();
  int d = tid >> 2, seg = (tid & 3) * 32;
  size_t obase = ((size_t)bh * HD + d) * LSEQ + lt * 128 + seg;
  for (int i = 0; i < 32; i += 4) {
    ushort4 u;
    u.x = tile[seg + i][d];
    u.y = tile[seg + i + 1][d];
    u.z = tile[seg + i + 2][d];
    u.w = tile[seg + i + 3][d];
    *(ushort4*)(Vt + obase + i) = u;
  }
}

// ---------------------------------------------------------------- bf16 MFMA flash attention
__global__ __launch_bounds__(256, 2)
void attn_mfma(const unsigned short* __restrict__ Qb, const unsigned short* __restrict__ Kb,
               const unsigned short* __restrict__ Vt, unsigned short* __restrict__ ao) {
  __shared__ unsigned int plds[128 * 128];  // P in hi 16 bits, 32B-XOR swizzled
  int bh = blockIdx.y;
  int qt = blockIdx.x;
  int tid = threadIdx.x;
  int w = tid >> 6, l = tid & 63;
  int ln = l & 15, lq = l >> 4;
  size_t kvbase = (size_t)bh * LSEQ * HD;
  int qrow0 = qt * 128 + w * 32;

  bf16x8 qh[2][2];
#pragma unroll
  for (int mi = 0; mi < 2; ++mi)
#pragma unroll
    for (int ks = 0; ks < 2; ++ks) {
      size_t o = kvbase + (size_t)(qrow0 + mi * 16 + ln) * HD + ks * 32 + lq * 8;
      qh[mi][ks] = *(const bf16x8*)(Qb + o);
    }

  float l_run[2][4] = {};
  f32x4 oacc[2][4] = {};

  for (int kt = 0; kt < 8; ++kt) {
    int k0 = kt * 128;
    f32x4 sacc[2][8] = {};
#pragma unroll
    for (int ni = 0; ni < 8; ++ni) {
      size_t ko = kvbase + (size_t)(k0 + ni * 16 + ln) * HD + lq * 8;
      bf16x8 kh0 = *(const bf16x8*)(Kb + ko);
      bf16x8 kh1 = *(const bf16x8*)(Kb + ko + 32);
#pragma unroll
      for (int mi = 0; mi < 2; ++mi) {
        f32x4 a = sacc[mi][ni];
        a = __builtin_amdgcn_mfma_f32_16x16x32_bf16(qh[mi][0], kh0, a, 0, 0, 0);
        a = __builtin_amdgcn_mfma_f32_16x16x32_bf16(qh[mi][1], kh1, a, 0, 0, 0);
        sacc[mi][ni] = a;
      }
    }
#pragma unroll
    for (int mi = 0; mi < 2; ++mi)
#pragma unroll
      for (int j = 0; j < 4; ++j) {
        float rs = 0.f;
#pragma unroll
        for (int ni = 0; ni < 8; ++ni) {
          float p = __expf(sacc[mi][ni][j]);
          sacc[mi][ni][j] = p;
          rs += p;
        }
        rs += __shfl_xor(rs, 1);
        rs += __shfl_xor(rs, 2);
        rs += __shfl_xor(rs, 4);
        rs += __shfl_xor(rs, 8);
        l_run[mi][j] += rs;
      }
#pragma unroll
    for (int mi = 0; mi < 2; ++mi)
#pragma unroll
      for (int ni = 0; ni < 8; ++ni)
#pragma unroll
        for (int j = 0; j < 4; ++j) {
          int row = w * 32 + mi * 16 + lq * 4 + j;
          int col = ni * 16 + ln;
          unsigned int u = ((unsigned int)f2bf(sacc[mi][ni][j])) << 16;
          plds[row * 128 + (col ^ ((row & 3) << 3))] = u;
        }
    __syncthreads();
#pragma unroll
    for (int ksp = 0; ksp < 4; ++ksp) {
      bf16x8 ph[2];
#pragma unroll
      for (int mi = 0; mi < 2; ++mi) {
        int row = w * 32 + mi * 16 + ln;
        int c0 = ksp * 32 + lq * 8;
        const unsigned int* pp = &plds[row * 128 + (c0 ^ ((row & 3) << 3))];
        uint4 u0 = *(const uint4*)pp;
        uint4 u1 = *(const uint4*)(pp + 4);
        unsigned int uu[8] = {u0.x, u0.y, u0.z, u0.w, u1.x, u1.y, u1.z, u1.w};
        U8 uh;
#pragma unroll
        for (int jj = 0; jj < 8; ++jj) uh.u[jj] = (unsigned short)(uu[jj] >> 16);
        ph[mi] = uh.b;
      }
#pragma unroll
      for (int ni = 0; ni < 4; ++ni) {
        size_t vo = kvbase + (size_t)(ni * 16 + ln) * LSEQ + k0 + ksp * 32 + lq * 8;
        bf16x8 vh = *(const bf16x8*)(Vt + vo);
#pragma unroll
        for (int mi = 0; mi < 2; ++mi)
          oacc[mi][ni] = __builtin_amdgcn_mfma_f32_16x16x32_bf16(ph[mi], vh, oacc[mi][ni], 0, 0, 0);
      }
    }
    __syncthreads();
  }

  int b = bh >> 4, hh = bh & 15;
#pragma unroll
  for (int mi = 0; mi < 2; ++mi) {
    float inv[4];
#pragma unroll
    for (int j = 0; j < 4; ++j) inv[j] = 1.0f / l_run[mi][j];
#pragma unroll
    for (int ni = 0; ni < 4; ++ni)
#pragma unroll
      for (int j = 0; j < 4; ++j) {
        int tok = b * 1024 + qt * 128 + w * 32 + mi * 16 + lq * 4 + j;
        int col = hh * 64 + ni * 16 + ln;
        ao[(size_t)tok * DMODEL + col] = f2bf(oacc[mi][ni][j] * inv[j]);
      }
  }
}

// ---------------------------------------------------------------- gating (exact f32), top-2, counts
__global__ __launch_bounds__(256)
void gate_kernel(const float* __restrict__ hn, const float* __restrict__ gw,
                 const float* __restrict__ bias, int* __restrict__ ti,
                 float* __restrict__ tw, int* __restrict__ icnt,
                 float* __restrict__ counts_out) {
  int t = blockIdx.x * 4 + (threadIdx.x >> 6);
  int lane = threadIdx.x & 63;
  const float* hrow = hn + (size_t)t * DMODEL;
  float acc[NEXP];
#pragma unroll
  for (int e = 0; e < NEXP; ++e) acc[e] = 0.f;
  for (int d = lane; d < DMODEL; d += 64) {
    float hv = hrow[d];
#pragma unroll
    for (int e = 0; e < NEXP; ++e) acc[e] += hv * gw[e * DMODEL + d];
  }
#pragma unroll
  for (int e = 0; e < NEXP; ++e)
#pragma unroll
    for (int off = 32; off > 0; off >>= 1) acc[e] += __shfl_xor(acc[e], off);
  if (lane == 0) {
    float lg[NEXP], ex[NEXP];
    float mx = -1e30f;
#pragma unroll
    for (int e = 0; e < NEXP; ++e) {
      lg[e] = acc[e] + bias[e];
      mx = fmaxf(mx, lg[e]);
    }
#pragma unroll
    for (int e = 0; e < NEXP; ++e) ex[e] = expf(lg[e] - mx);
    int i0 = 0;
    float p0 = ex[0];
#pragma unroll
    for (int e = 1; e < NEXP; ++e)
      if (ex[e] > p0) { p0 = ex[e]; i0 = e; }
    int i1 = -1;
    float p1 = -1.f;
#pragma unroll
    for (int e = 0; e < NEXP; ++e)
      if (e != i0 && ex[e] > p1) { p1 = ex[e]; i1 = e; }
    float wsum = p0 + p1;
    ti[2 * t] = i0;
    ti[2 * t + 1] = i1;
    tw[2 * t] = p0 / wsum;
    tw[2 * t + 1] = p1 / wsum;
    atomicAdd(&icnt[i0], 1);
    atomicAdd(&icnt[i1], 1);
    atomicAdd(&counts_out[i0], 1.0f);
    atomicAdd(&counts_out[i1], 1.0f);
  }
}

__global__ void init_kernel(float* __restrict__ counts_out, int* __restrict__ icnt,
                            int* __restrict__ cursor) {
  int i = threadIdx.x;
  if (i < NEXP) {
    counts_out[i] = 0.f;
    icnt[i] = 0;
    cursor[i] = 0;
  }
}

__global__ void scan_kernel(const int* __restrict__ icnt, int* __restrict__ ebase) {
  if (threadIdx.x == 0) {
    int s = 0;
    for (int e = 0; e < NEXP; ++e) {
      ebase[e] = s;
      s += icnt[e];
    }
  }
}

__global__ __launch_bounds__(256)
void scatter_kernel(const int* __restrict__ ti, const int* __restrict__ ebase,
                    int* __restrict__ cursor, int* __restrict__ tok2e) {
  int t = blockIdx.x * 256 + threadIdx.x;
#pragma unroll
  for (int s = 0; s < 2; ++s) {
    int e = ti[2 * t + s];
    int pos = atomicAdd(&cursor[e], 1);
    tok2e[ebase[e] + pos] = 2 * t + s;
  }
}

// out = x1 + tw0*y[2t] + tw1*y[2t+1]   (y in bf16)
__global__ __launch_bounds__(256)
void combine_kernel(const float* __restrict__ x1, const unsigned short* __restrict__ y,
                    const float* __restrict__ tw, float* __restrict__ out) {
  int idx = blockIdx.x * 256 + threadIdx.x;
  int t = idx >> 8, c = idx & 255;
  float w0 = tw[2 * t], w1 = tw[2 * t + 1];
  float4 a = ((const float4*)x1)[idx];
  const unsigned short* y0 = y + (size_t)(2 * t) * DMODEL + c * 4;
  const unsigned short* y1 = y0 + DMODEL;
  ushort4 u0 = *(const ushort4*)y0;
  ushort4 u1 = *(const ushort4*)y1;
  float4 o;
  o.x = a.x + w0 * bf2f(u0.x) + w1 * bf2f(u1.x);
  o.y = a.y + w0 * bf2f(u0.y) + w1 * bf2f(u1.y);
  o.z = a.z + w0 * bf2f(u0.z) + w1 * bf2f(u1.z);
  o.w = a.w + w0 * bf2f(u0.w) + w1 * bf2f(u1.w);
  ((float4*)out)[idx] = o;
}

// ----------------------------------------------------------------
extern "C" void kernel_launch(void* const* d_in, const int* in_sizes, int n_in,
                              void* d_out, int out_size, void* d_ws, size_t ws_size,
                              hipStream_t stream) {
  (void)in_sizes; (void)n_in; (void)ws_size;
  const float* x = (const float*)d_in[0];
  const float* tsq = (const float*)d_in[1];
  const float* tskv = (const float*)d_in[2];
  const float* attn_nw = (const float*)d_in[3];
  const float* ffn_nw = (const float*)d_in[4];
  const float* w_kv_c = (const float*)d_in[5];
  const float* w_kc_up = (const float*)d_in[6];
  const float* w_vc_up = (const float*)d_in[7];
  const float* w_qr = (const float*)d_in[8];
  const float* w_kr = (const float*)d_in[9];
  const float* w_o = (const float*)d_in[10];
  const float* gate_w = (const float*)d_in[11];
  const float* expert_bias = (const float*)d_in[12];
  const float* w1 = (const float*)d_in[13];
  const float* w2 = (const float*)d_in[14];

  float* out = (float*)d_out;
  float* counts_out = out + (out_size - NEXP);

  char* ws = (char*)d_ws;
  size_t off = 0;
  auto alloc = [&](size_t bytes) {
    char* p = ws + off;
    off += (bytes + 255) & ~(size_t)255;
    return p;
  };
  // LAYOUT INVARIANT: qb..kcb stays 64MB contiguous (wx8 overlay, 33.6MB, for MoE fp8 weights).
  float* h   = (float*)alloc((size_t)NTOK * DMODEL * 4);   // h, later x1
  float* qb  = (float*)alloc((size_t)NTOK * DMODEL * 4);   // q_r, later hn f32; wx8 overlay base
  float* kb  = (float*)alloc((size_t)NTOK * DMODEL * 4);   // k_r
  float* vb  = (float*)alloc((size_t)NTOK * DMODEL * 4);   // 16MB slot; first 8MB = bf16 v_c (vbb)
  float* kcb = (float*)alloc((size_t)NTOK * DMODEL * 4);   // k_c
  float* ckv = (float*)alloc((size_t)NTOK * DC * 4);
  unsigned short* yb  = (unsigned short*)alloc((size_t)NTOK * 2 * DMODEL * 2);  // bf16 y
  unsigned short* hb  = (unsigned short*)alloc((size_t)NTOK * DMODEL * 2);      // bf16 h
  unsigned short* hmid = (unsigned short*)alloc((size_t)NTOK * 2 * DFF2 * 2);   // 64MB slot (attn overlay + fp8 hmid)
  unsigned short* ckvb = (unsigned short*)alloc((size_t)NTOK * DC * 2);         // bf16 ckv
  unsigned short* wbuf = (unsigned short*)alloc((size_t)2176 * DMODEL * 2);     // bf16 concat weight staging
  float* tw  = (float*)alloc((size_t)NTOK * 2 * 4);
  int* ti    = (int*)alloc((size_t)NTOK * 2 * 4);
  int* tok2e = (int*)alloc((size_t)NTOK * 2 * 4);
  int* icnt  = (int*)alloc(NEXP * 4);
  int* ebase = (int*)alloc(NEXP * 4);
  int* cursor = (int*)alloc(NEXP * 4);
  unsigned char* hn8 = (unsigned char*)alloc((size_t)NTOK * DMODEL);            // fp8 hn (4MB)

  unsigned short* vbb = (unsigned short*)vb;  // bf16 v_c inside the vb slot
  // attention buffers overlay hmid slot (dead until moe FFN1): 4×8MB = 32MB
  unsigned short* Qb = hmid;
  unsigned short* Kb = hmid + (size_t)4 * 1024 * 1024;
  unsigned short* Vt = hmid + (size_t)8 * 1024 * 1024;
  unsigned short* ao = hmid + (size_t)12 * 1024 * 1024;
  // fp8 hmid in back half of the hmid slot (32MB; front 32MB holds the attn overlay, dead by FFN1)
  unsigned char* hmid8 = (unsigned char*)(hmid + (size_t)16 * 1024 * 1024);
  // MoE fp8 weight overlay on qb..kcb (33.6MB needed, 64MB available, dead after gate)
  unsigned char* wx8 = (unsigned char*)qb;

  init_kernel<<<1, 64, 0, stream>>>(counts_out, icnt, cursor);
  rmsnorm_kernel<<<NTOK, 256, 0, stream>>>(x, attn_nw, nullptr, hb, nullptr);
  // merged projection 1: [q_r | k_r | c_kv] = h @ [w_qr; w_kr; w_kv_c]^T   (N = 2176)
  cvt3_bf16_kernel<<<1024, 256, 0, stream>>>(w_qr, DMODEL * DMODEL / 8,
                                             w_kr, DMODEL * DMODEL / 8,
                                             w_kv_c, DC * DMODEL / 8, wbuf);
  gemm_proj<<<dim3(17, 32), 256, 0, stream>>>(hb, wbuf, qb, kb, ckv, nullptr,
                                              1024, 2048, DMODEL, DMODEL, DC, DMODEL);
  cvt_bf16_kernel<<<256, 256, 0, stream>>>(ckv, ckvb, NTOK * DC / 8);
  // merged projection 2: [k_c | v_c(bf16)] = c_kv @ [w_kc_up; w_vc_up]^T   (N = 2048, K = 128)
  cvt3_bf16_kernel<<<64, 256, 0, stream>>>(w_kc_up, DMODEL * DC / 8,
                                           w_vc_up, DMODEL * DC / 8,
                                           w_vc_up, 0, wbuf);
  gemm_proj<<<dim3(16, 32), 256, 0, stream>>>(ckvb, wbuf, kcb, nullptr, nullptr, vbb,
                                              1024, 2048, DMODEL, DMODEL, DMODEL, DC);
  // fused rope + ksum + bf16 relayout
  rope_qk_kernel<<<NTOK, 256, 0, stream>>>(qb, kb, kcb, tsq, tskv, Qb, Kb);
  v_split_kernel<<<dim3(64, 8), 256, 0, stream>>>(vbb, Vt);
  attn_mfma<<<dim3(8, 64), 256, 0, stream>>>(Qb, Kb, Vt, ao);
  // x1 = attn_out @ w_o^T + x
  cvt_bf16_kernel<<<512, 256, 0, stream>>>(w_o, wbuf, DMODEL * DMODEL / 8);
  gemm_bf16<<<dim3(8, 32), 256, 0, stream>>>(ao, wbuf, h, x, DMODEL, DMODEL);
  // FFN norm + gate + route (f32 exact gate path; fp8 hn for MoE)
  rmsnorm_kernel<<<NTOK, 256, 0, stream>>>(h, ffn_nw, qb, nullptr, hn8);
  gate_kernel<<<NTOK / 4, 256, 0, stream>>>(qb, gate_w, expert_bias, ti, tw, icnt, counts_out);
  scan_kernel<<<1, 64, 0, stream>>>(icnt, ebase);
  scatter_kernel<<<NTOK / 256, 256, 0, stream>>>(ti, ebase, cursor, tok2e);
  // MoE: fp8 e4m3 grouped GEMMs (R7 schedule, halved operand bytes)
  cvt_fp8_kernel<<<2048, 256, 0, stream>>>(w1, wx8, NEXP * DFF2 * DMODEL / 8);
  moe_fp8<0><<<dim3(DFF2 / 128, NTOK / 128, NEXP), 256, 0, stream>>>(
      hn8, wx8, hmid8, nullptr, tok2e, ebase, icnt);
  cvt_fp8_kernel<<<2048, 256, 0, stream>>>(w2, wx8, NEXP * DMODEL * DFF2 / 8);
  moe_fp8<1><<<dim3(DMODEL / 128, NTOK / 128, NEXP), 256, 0, stream>>>(
      hmid8, wx8, nullptr, yb, tok2e, ebase, icnt);
  combine_kernel<<<NTOK, 256, 0, stream>>>(h, yb, tw, out);
}

// Round 14
// 759.238 us; speedup vs baseline: 1.1275x; 1.1275x over previous
//
#include <hip/hip_runtime.h>
#include <hip/hip_bf16.h>

typedef __hip_bfloat16 bf16;
typedef __attribute__((ext_vector_type(8))) unsigned short ushort8v;
typedef __bf16 bf16x8 __attribute__((ext_vector_type(8)));
typedef float f32x4 __attribute__((ext_vector_type(4)));

#define NTOK 4096
#define DMODEL 1024
#define NHEADS 16
#define HD 64
#define DC 128
#define DFF2 4096
#define NEXP 8
#define LSEQ 1024
#define NBATCH 4
#define RMS_EPS 1.1920928955078125e-07f

union U8 { ushort8v u; bf16x8 b; };

__device__ __forceinline__ float bf2f(unsigned short u) {
  return __uint_as_float(((unsigned int)u) << 16);
}
__device__ __forceinline__ unsigned short f2bf(float f) {
  unsigned int u = __float_as_uint(f);
  unsigned int r = (u + 0x7FFF + ((u >> 16) & 1)) >> 16;
  return (unsigned short)r;
}
__device__ __forceinline__ void gload_lds16(const unsigned short* g, unsigned short* l) {
  __builtin_amdgcn_global_load_lds(
      (__attribute__((address_space(1))) void*)(const_cast<unsigned short*>(g)),
      (__attribute__((address_space(3))) void*)(l), 16, 0, 0);
}

// ---------------------------------------------------------------- rmsnorm (optional extra bf16 output)
__global__ __launch_bounds__(256)
void rmsnorm_kernel(const float* __restrict__ x, const float* __restrict__ w,
                    float* __restrict__ o, unsigned short* __restrict__ ob) {
  int t = blockIdx.x;
  int tid = threadIdx.x;
  const float4* xr = (const float4*)(x + (size_t)t * DMODEL);
  float4 v = xr[tid];
  float ss = v.x * v.x + v.y * v.y + v.z * v.z + v.w * v.w;
#pragma unroll
  for (int off = 32; off > 0; off >>= 1) ss += __shfl_xor(ss, off);
  __shared__ float red[4];
  int wid = tid >> 6, lane = tid & 63;
  if (lane == 0) red[wid] = ss;
  __syncthreads();
  float tot = red[0] + red[1] + red[2] + red[3];
  float scale = rsqrtf(tot * (1.0f / DMODEL) + RMS_EPS);
  float4 wv = ((const float4*)w)[tid];
  float4 ov;
  ov.x = v.x * scale * wv.x;
  ov.y = v.y * scale * wv.y;
  ov.z = v.z * scale * wv.z;
  ov.w = v.w * scale * wv.w;
  if (o) ((float4*)(o + (size_t)t * DMODEL))[tid] = ov;
  if (ob) {
    unsigned short* orow = ob + (size_t)t * DMODEL + tid * 4;
    orow[0] = f2bf(ov.x); orow[1] = f2bf(ov.y);
    orow[2] = f2bf(ov.z); orow[3] = f2bf(ov.w);
  }
}

// ---------------------------------------------------------------- f32 -> bf16 conversion (single src)
__global__ __launch_bounds__(256)
void cvt_bf16_kernel(const float* __restrict__ in, unsigned short* __restrict__ o, int n8) {
  int stride = gridDim.x * 256;
  for (int i = blockIdx.x * 256 + threadIdx.x; i < n8; i += stride) {
    float4 a = ((const float4*)in)[2 * i];
    float4 b = ((const float4*)in)[2 * i + 1];
    ushort8v u;
    u[0] = f2bf(a.x); u[1] = f2bf(a.y); u[2] = f2bf(a.z); u[3] = f2bf(a.w);
    u[4] = f2bf(b.x); u[5] = f2bf(b.y); u[6] = f2bf(b.z); u[7] = f2bf(b.w);
    *(ushort8v*)(o + (size_t)i * 8) = u;
  }
}

// ---------------------------------------------------------------- segmented f32 -> bf16 (up to 3 srcs, concat dst)
__global__ __launch_bounds__(256)
void cvt3_bf16_kernel(const float* __restrict__ s0, int n0,
                      const float* __restrict__ s1, int n1,
                      const float* __restrict__ s2, int n2,
                      unsigned short* __restrict__ o) {
  int total = n0 + n1 + n2;
  int stride = gridDim.x * 256;
  for (int i = blockIdx.x * 256 + threadIdx.x; i < total; i += stride) {
    const float* src;
    int li = i;
    if (li < n0) src = s0;
    else if ((li -= n0) < n1) src = s1;
    else { li -= n1; src = s2; }
    float4 a = ((const float4*)src)[2 * li];
    float4 b = ((const float4*)src)[2 * li + 1];
    ushort8v u;
    u[0] = f2bf(a.x); u[1] = f2bf(a.y); u[2] = f2bf(a.z); u[3] = f2bf(a.w);
    u[4] = f2bf(b.x); u[5] = f2bf(b.y); u[6] = f2bf(b.z); u[7] = f2bf(b.w);
    *(ushort8v*)(o + (size_t)i * 8) = u;
  }
}

// ---------------------------------------------------------------- dense bf16 MFMA GEMM (m97 structure, 128x128), + addend
__global__ __launch_bounds__(256)
void gemm_bf16(const unsigned short* __restrict__ Ab, const unsigned short* __restrict__ Wb,
               float* __restrict__ Cf, const float* __restrict__ addend, int N, int K) {
  __shared__ __align__(16) unsigned short As[128 * 64];
  __shared__ __align__(16) unsigned short Bs[128 * 64];
  int row0 = blockIdx.y * 128;
  int col0 = blockIdx.x * 128;
  int tid = threadIdx.x;
  int w = tid >> 6, l = tid & 63;
  int lr = l >> 3;
  int lc = (l & 7) * 8;

  const unsigned short* aSrc[4];
  const unsigned short* bSrc[4];
#pragma unroll
  for (int i = 0; i < 4; ++i) {
    aSrc[i] = Ab + (size_t)(row0 + i * 32 + w * 8 + lr) * K + lc;
    bSrc[i] = Wb + (size_t)(col0 + i * 32 + w * 8 + lr) * K + lc;
  }

  f32x4 acc[4][4] = {};
  int wr = w >> 1, wc = w & 1;
  int ln = l & 15, lq = l >> 4;

  for (int k0 = 0; k0 < K; k0 += 64) {
#pragma unroll
    for (int i = 0; i < 4; ++i) {
      gload_lds16(aSrc[i] + k0, &As[(i * 4 + w) * 512]);
      gload_lds16(bSrc[i] + k0, &Bs[(i * 4 + w) * 512]);
    }
    __syncthreads();
#pragma unroll
    for (int kk = 0; kk < 2; ++kk) {
      bf16x8 af[4], bfr[4];
#pragma unroll
      for (int m = 0; m < 4; ++m)
        af[m] = *(const bf16x8*)&As[(wr * 64 + m * 16 + ln) * 64 + kk * 32 + lq * 8];
#pragma unroll
      for (int n = 0; n < 4; ++n)
        bfr[n] = *(const bf16x8*)&Bs[(wc * 64 + n * 16 + ln) * 64 + kk * 32 + lq * 8];
#pragma unroll
      for (int m = 0; m < 4; ++m)
#pragma unroll
        for (int n = 0; n < 4; ++n)
          acc[m][n] = __builtin_amdgcn_mfma_f32_16x16x32_bf16(af[m], bfr[n], acc[m][n], 0, 0, 0);
    }
    __syncthreads();
  }

#pragma unroll
  for (int m = 0; m < 4; ++m) {
#pragma unroll
    for (int j = 0; j < 4; ++j) {
      int row = row0 + wr * 64 + m * 16 + lq * 4 + j;
      float* crow = Cf + (size_t)row * N + col0 + wc * 64 + ln;
      const float* arow = addend ? addend + (size_t)row * N + col0 + wc * 64 + ln : nullptr;
#pragma unroll
      for (int n = 0; n < 4; ++n) {
        float vv = acc[m][n][j];
        if (addend) vv += arow[n * 16];
        crow[n * 16] = vv;
      }
    }
  }
}

// ---------------------------------------------------------------- merged-projection GEMM (3-way dest epilogue)
// segment 1 [c1,c2) optionally bf16 via d1b; segment 2 [c2,..) optionally bf16 via d2b.
__global__ __launch_bounds__(256)
void gemm_proj(const unsigned short* __restrict__ Ab, const unsigned short* __restrict__ Wcat,
               float* __restrict__ d0, float* __restrict__ d1, float* __restrict__ d2,
               unsigned short* __restrict__ d1b, unsigned short* __restrict__ d2b,
               int c1, int c2, int s0, int s1, int s2, int K) {
  __shared__ __align__(16) unsigned short As[128 * 64];
  __shared__ __align__(16) unsigned short Bs[128 * 64];
  int row0 = blockIdx.y * 128;
  int col0 = blockIdx.x * 128;
  int tid = threadIdx.x;
  int w = tid >> 6, l = tid & 63;
  int lr = l >> 3;
  int lc = (l & 7) * 8;

  const unsigned short* aSrc[4];
  const unsigned short* bSrc[4];
#pragma unroll
  for (int i = 0; i < 4; ++i) {
    aSrc[i] = Ab + (size_t)(row0 + i * 32 + w * 8 + lr) * K + lc;
    bSrc[i] = Wcat + (size_t)(col0 + i * 32 + w * 8 + lr) * K + lc;
  }

  f32x4 acc[4][4] = {};
  int wr = w >> 1, wc = w & 1;
  int ln = l & 15, lq = l >> 4;

  for (int k0 = 0; k0 < K; k0 += 64) {
#pragma unroll
    for (int i = 0; i < 4; ++i) {
      gload_lds16(aSrc[i] + k0, &As[(i * 4 + w) * 512]);
      gload_lds16(bSrc[i] + k0, &Bs[(i * 4 + w) * 512]);
    }
    __syncthreads();
#pragma unroll
    for (int kk = 0; kk < 2; ++kk) {
      bf16x8 af[4], bfr[4];
#pragma unroll
      for (int m = 0; m < 4; ++m)
        af[m] = *(const bf16x8*)&As[(wr * 64 + m * 16 + ln) * 64 + kk * 32 + lq * 8];
#pragma unroll
      for (int n = 0; n < 4; ++n)
        bfr[n] = *(const bf16x8*)&Bs[(wc * 64 + n * 16 + ln) * 64 + kk * 32 + lq * 8];
#pragma unroll
      for (int m = 0; m < 4; ++m)
#pragma unroll
        for (int n = 0; n < 4; ++n)
          acc[m][n] = __builtin_amdgcn_mfma_f32_16x16x32_bf16(af[m], bfr[n], acc[m][n], 0, 0, 0);
    }
    __syncthreads();
  }

  bool seg1 = (col0 >= c1) && (col0 < c2);
  bool seg2 = (col0 >= c2);
  unsigned short* dbf = (seg1 && d1b) ? d1b : (seg2 && d2b) ? d2b : nullptr;
  if (dbf) {
    int cb = seg1 ? c1 : c2;
    int stride = seg1 ? s1 : s2;
#pragma unroll
    for (int m = 0; m < 4; ++m) {
#pragma unroll
      for (int j = 0; j < 4; ++j) {
        int row = row0 + wr * 64 + m * 16 + lq * 4 + j;
        unsigned short* crow = dbf + (size_t)row * stride + (col0 - cb) + wc * 64 + ln;
#pragma unroll
        for (int n = 0; n < 4; ++n) crow[n * 16] = f2bf(acc[m][n][j]);
      }
    }
    return;
  }
  float* dst;
  int cb, stride;
  if (col0 < c1) { dst = d0; cb = 0; stride = s0; }
  else if (seg1) { dst = d1; cb = c1; stride = s1; }
  else { dst = d2; cb = c2; stride = s2; }
#pragma unroll
  for (int m = 0; m < 4; ++m) {
#pragma unroll
    for (int j = 0; j < 4; ++j) {
      int row = row0 + wr * 64 + m * 16 + lq * 4 + j;
      float* crow = dst + (size_t)row * stride + (col0 - cb) + wc * 64 + ln;
#pragma unroll
      for (int n = 0; n < 4; ++n) crow[n * 16] = acc[m][n][j];
    }
  }
}

// ---------------------------------------------------------------- bf16 MFMA grouped GEMM (MoE), 128x128 — R7-exact (best of 6 measured)
// N-fastest grid: W streams sequentially, A-tile stays L2-hot.
// MODE 0 (FFN1): A gathered via tok2e>>1; silu -> hmid.  MODE 1 (FFN2): scatter to y.
template <int MODE>
__global__ __launch_bounds__(256)
void moe_mfma(const unsigned short* __restrict__ A, const unsigned short* __restrict__ Wb,
              unsigned short* __restrict__ Cout, const int* __restrict__ tok2e,
              const int* __restrict__ ebase, const int* __restrict__ icnt) {
  constexpr int N = (MODE == 0) ? DFF2 : DMODEL;
  constexpr int K = (MODE == 0) ? DMODEL : DFF2;
  __shared__ __align__(16) unsigned short As[128 * 64];
  __shared__ __align__(16) unsigned short Bs[128 * 64];
  int e = blockIdx.z;
  int base = ebase[e];
  int cnt = icnt[e];
  int row0 = blockIdx.y * 128;
  if (row0 >= cnt) return;
  int col0 = blockIdx.x * 128;
  int tid = threadIdx.x;
  int w = tid >> 6, l = tid & 63;
  int lr = l >> 3;
  int lc = (l & 7) * 8;

  const unsigned short* aSrc[4];
  const unsigned short* bSrc[4];
#pragma unroll
  for (int i = 0; i < 4; ++i) {
    int r = row0 + i * 32 + w * 8 + lr;
    r = r < cnt ? r : cnt - 1;
    if (MODE == 0) {
      int tok = tok2e[base + r] >> 1;
      aSrc[i] = A + (size_t)tok * K + lc;
    } else {
      aSrc[i] = A + (size_t)(base + r) * K + lc;
    }
    int nrow = col0 + i * 32 + w * 8 + lr;
    bSrc[i] = Wb + (size_t)e * N * K + (size_t)nrow * K + lc;
  }

  f32x4 acc[4][4] = {};
  int wr = w >> 1, wc = w & 1;
  int ln16 = l & 15, lq = l >> 4;

  for (int k0 = 0; k0 < K; k0 += 64) {
#pragma unroll
    for (int i = 0; i < 4; ++i) {
      gload_lds16(aSrc[i] + k0, &As[(i * 4 + w) * 512]);
      gload_lds16(bSrc[i] + k0, &Bs[(i * 4 + w) * 512]);
    }
    __syncthreads();
#pragma unroll
    for (int kk = 0; kk < 2; ++kk) {
      bf16x8 af[4], bfr[4];
#pragma unroll
      for (int m = 0; m < 4; ++m)
        af[m] = *(const bf16x8*)&As[(wr * 64 + m * 16 + ln16) * 64 + kk * 32 + lq * 8];
#pragma unroll
      for (int n = 0; n < 4; ++n)
        bfr[n] = *(const bf16x8*)&Bs[(wc * 64 + n * 16 + ln16) * 64 + kk * 32 + lq * 8];
#pragma unroll
      for (int m = 0; m < 4; ++m)
#pragma unroll
        for (int n = 0; n < 4; ++n)
          acc[m][n] = __builtin_amdgcn_mfma_f32_16x16x32_bf16(af[m], bfr[n], acc[m][n], 0, 0, 0);
    }
    __syncthreads();
  }

#pragma unroll
  for (int m = 0; m < 4; ++m) {
#pragma unroll
    for (int j = 0; j < 4; ++j) {
      int r = row0 + wr * 64 + m * 16 + lq * 4 + j;
      if (r < cnt) {
        if (MODE == 0) {
          unsigned short* orow = Cout + (size_t)(base + r) * N + col0 + wc * 64 + ln16;
#pragma unroll
          for (int n = 0; n < 4; ++n) {
            float v = acc[m][n][j];
            float s = v / (1.f + __expf(-v));
            orow[n * 16] = f2bf(s);
          }
        } else {
          int t2 = tok2e[base + r];
          unsigned short* orow = Cout + (size_t)t2 * N + col0 + wc * 64 + ln16;
#pragma unroll
          for (int n = 0; n < 4; ++n) orow[n * 16] = f2bf(acc[m][n][j]);
        }
      }
    }
  }
}

// ---------------------------------------------------------------- fused rope (cos-only) + ksum + bf16 per-(b,h) relayout
__global__ __launch_bounds__(256)
void rope_qk_kernel(const float* __restrict__ q, const float* __restrict__ k,
                    const float* __restrict__ kc, const float* __restrict__ tsq,
                    const float* __restrict__ tskv,
                    unsigned short* __restrict__ Qb, unsigned short* __restrict__ Kb) {
  int t = blockIdx.x;
  int tid = threadIdx.x;
  __shared__ float cq[32], ck[32];
  if (tid < 32) {
    float fr = __expf(-(float)(2 * tid) * (1.0f / HD) * 9.210340371976184f);  // ln(10000)
    cq[tid] = cosf(tsq[t] * fr);
    ck[tid] = cosf(tskv[t] * fr);
  }
  __syncthreads();
  int b = t >> 10, lrow = t & 1023;
  size_t rb = (size_t)t * DMODEL;
  for (int p = tid; p < 512; p += 256) {
    int hh = p >> 5, d = p & 31;
    int c1 = hh * 64 + d, c2 = c1 + 32;
    float cqd = cq[d], ckd = ck[d];
    float q1 = q[rb + c1], q2 = q[rb + c2];
    float rq1 = (q1 * cqd - q2 * ckd) * 0.125f;
    float rq2 = (q2 * cqd + q1 * ckd) * 0.125f;
    float k1 = k[rb + c1], k2 = k[rb + c2];
    float rk1 = (k1 * cqd - k2 * ckd) + kc[rb + c1];
    float rk2 = (k2 * cqd + k1 * ckd) + kc[rb + c2];
    size_t dst = ((size_t)(b * NHEADS + hh) * LSEQ + lrow) * HD;
    Qb[dst + d] = f2bf(rq1);
    Qb[dst + d + 32] = f2bf(rq2);
    Kb[dst + d] = f2bf(rk1);
    Kb[dst + d + 32] = f2bf(rk2);
  }
}

// ---------------------------------------------------------------- v transpose (bf16 in, bf16 out)  [bh][64][1024]
__global__ __launch_bounds__(256)
void v_split_kernel(const unsigned short* __restrict__ vbb, unsigned short* __restrict__ Vt) {
  __shared__ unsigned short tile[128][72];
  int bh = blockIdx.x;
  int lt = blockIdx.y;
  int b = bh >> 4, hh = bh & 15;
  int tid = threadIdx.x;
#pragma unroll
  for (int pass = 0; pass < 8; ++pass) {
    int r = pass * 16 + (tid >> 4);
    int dq = (tid & 15) * 4;
    ushort4 vv = *(const ushort4*)(vbb + (size_t)(b * 1024 + lt * 128 + r) * DMODEL + hh * 64 + dq);
    tile[r][dq + 0] = vv.x; tile[r][dq + 1] = vv.y;
    tile[r][dq + 2] = vv.z; tile[r][dq + 3] = vv.w;
  }
  __syncthreads();
  int d = tid >> 2, seg = (tid & 3) * 32;
  size_t obase = ((size_t)bh * HD + d) * LSEQ + lt * 128 + seg;
  for (int i = 0; i < 32; i += 4) {
    ushort4 u;
    u.x = tile[seg + i][d];
    u.y = tile[seg + i + 1][d];
    u.z = tile[seg + i + 2][d];
    u.w = tile[seg + i + 3][d];
    *(ushort4*)(Vt + obase + i) = u;
  }
}

// ---------------------------------------------------------------- bf16 MFMA flash attention
__global__ __launch_bounds__(256, 2)
void attn_mfma(const unsigned short* __restrict__ Qb, const unsigned short* __restrict__ Kb,
               const unsigned short* __restrict__ Vt, unsigned short* __restrict__ ao) {
  __shared__ unsigned int plds[128 * 128];  // P in hi 16 bits, 32B-XOR swizzled
  int bh = blockIdx.y;
  int qt = blockIdx.x;
  int tid = threadIdx.x;
  int w = tid >> 6, l = tid & 63;
  int ln = l & 15, lq = l >> 4;
  size_t kvbase = (size_t)bh * LSEQ * HD;
  int qrow0 = qt * 128 + w * 32;

  bf16x8 qh[2][2];
#pragma unroll
  for (int mi = 0; mi < 2; ++mi)
#pragma unroll
    for (int ks = 0; ks < 2; ++ks) {
      size_t o = kvbase + (size_t)(qrow0 + mi * 16 + ln) * HD + ks * 32 + lq * 8;
      qh[mi][ks] = *(const bf16x8*)(Qb + o);
    }

  float l_run[2][4] = {};
  f32x4 oacc[2][4] = {};

  for (int kt = 0; kt < 8; ++kt) {
    int k0 = kt * 128;
    f32x4 sacc[2][8] = {};
#pragma unroll
    for (int ni = 0; ni < 8; ++ni) {
      size_t ko = kvbase + (size_t)(k0 + ni * 16 + ln) * HD + lq * 8;
      bf16x8 kh0 = *(const bf16x8*)(Kb + ko);
      bf16x8 kh1 = *(const bf16x8*)(Kb + ko + 32);
#pragma unroll
      for (int mi = 0; mi < 2; ++mi) {
        f32x4 a = sacc[mi][ni];
        a = __builtin_amdgcn_mfma_f32_16x16x32_bf16(qh[mi][0], kh0, a, 0, 0, 0);
        a = __builtin_amdgcn_mfma_f32_16x16x32_bf16(qh[mi][1], kh1, a, 0, 0, 0);
        sacc[mi][ni] = a;
      }
    }
#pragma unroll
    for (int mi = 0; mi < 2; ++mi)
#pragma unroll
      for (int j = 0; j < 4; ++j) {
        float rs = 0.f;
#pragma unroll
        for (int ni = 0; ni < 8; ++ni) {
          float p = __expf(sacc[mi][ni][j]);
          sacc[mi][ni][j] = p;
          rs += p;
        }
        rs += __shfl_xor(rs, 1);
        rs += __shfl_xor(rs, 2);
        rs += __shfl_xor(rs, 4);
        rs += __shfl_xor(rs, 8);
        l_run[mi][j] += rs;
      }
#pragma unroll
    for (int mi = 0; mi < 2; ++mi)
#pragma unroll
      for (int ni = 0; ni < 8; ++ni)
#pragma unroll
        for (int j = 0; j < 4; ++j) {
          int row = w * 32 + mi * 16 + lq * 4 + j;
          int col = ni * 16 + ln;
          unsigned int u = ((unsigned int)f2bf(sacc[mi][ni][j])) << 16;
          plds[row * 128 + (col ^ ((row & 3) << 3))] = u;
        }
    __syncthreads();
#pragma unroll
    for (int ksp = 0; ksp < 4; ++ksp) {
      bf16x8 ph[2];
#pragma unroll
      for (int mi = 0; mi < 2; ++mi) {
        int row = w * 32 + mi * 16 + ln;
        int c0 = ksp * 32 + lq * 8;
        const unsigned int* pp = &plds[row * 128 + (c0 ^ ((row & 3) << 3))];
        uint4 u0 = *(const uint4*)pp;
        uint4 u1 = *(const uint4*)(pp + 4);
        unsigned int uu[8] = {u0.x, u0.y, u0.z, u0.w, u1.x, u1.y, u1.z, u1.w};
        U8 uh;
#pragma unroll
        for (int jj = 0; jj < 8; ++jj) uh.u[jj] = (unsigned short)(uu[jj] >> 16);
        ph[mi] = uh.b;
      }
#pragma unroll
      for (int ni = 0; ni < 4; ++ni) {
        size_t vo = kvbase + (size_t)(ni * 16 + ln) * LSEQ + k0 + ksp * 32 + lq * 8;
        bf16x8 vh = *(const bf16x8*)(Vt + vo);
#pragma unroll
        for (int mi = 0; mi < 2; ++mi)
          oacc[mi][ni] = __builtin_amdgcn_mfma_f32_16x16x32_bf16(ph[mi], vh, oacc[mi][ni], 0, 0, 0);
      }
    }
    __syncthreads();
  }

  int b = bh >> 4, hh = bh & 15;
#pragma unroll
  for (int mi = 0; mi < 2; ++mi) {
    float inv[4];
#pragma unroll
    for (int j = 0; j < 4; ++j) inv[j] = 1.0f / l_run[mi][j];
#pragma unroll
    for (int ni = 0; ni < 4; ++ni)
#pragma unroll
      for (int j = 0; j < 4; ++j) {
        int tok = b * 1024 + qt * 128 + w * 32 + mi * 16 + lq * 4 + j;
        int col = hh * 64 + ni * 16 + ln;
        ao[(size_t)tok * DMODEL + col] = f2bf(oacc[mi][ni][j] * inv[j]);
      }
  }
}

// ---------------------------------------------------------------- gating (exact f32), top-2, counts
__global__ __launch_bounds__(256)
void gate_kernel(const float* __restrict__ hn, const float* __restrict__ gw,
                 const float* __restrict__ bias, int* __restrict__ ti,
                 float* __restrict__ tw, int* __restrict__ icnt,
                 float* __restrict__ counts_out) {
  int t = blockIdx.x * 4 + (threadIdx.x >> 6);
  int lane = threadIdx.x & 63;
  const float* hrow = hn + (size_t)t * DMODEL;
  float acc[NEXP];
#pragma unroll
  for (int e = 0; e < NEXP; ++e) acc[e] = 0.f;
  for (int d = lane; d < DMODEL; d += 64) {
    float hv = hrow[d];
#pragma unroll
    for (int e = 0; e < NEXP; ++e) acc[e] += hv * gw[e * DMODEL + d];
  }
#pragma unroll
  for (int e = 0; e < NEXP; ++e)
#pragma unroll
    for (int off = 32; off > 0; off >>= 1) acc[e] += __shfl_xor(acc[e], off);
  if (lane == 0) {
    float lg[NEXP], ex[NEXP];
    float mx = -1e30f;
#pragma unroll
    for (int e = 0; e < NEXP; ++e) {
      lg[e] = acc[e] + bias[e];
      mx = fmaxf(mx, lg[e]);
    }
#pragma unroll
    for (int e = 0; e < NEXP; ++e) ex[e] = expf(lg[e] - mx);
    int i0 = 0;
    float p0 = ex[0];
#pragma unroll
    for (int e = 1; e < NEXP; ++e)
      if (ex[e] > p0) { p0 = ex[e]; i0 = e; }
    int i1 = -1;
    float p1 = -1.f;
#pragma unroll
    for (int e = 0; e < NEXP; ++e)
      if (e != i0 && ex[e] > p1) { p1 = ex[e]; i1 = e; }
    float wsum = p0 + p1;
    ti[2 * t] = i0;
    ti[2 * t + 1] = i1;
    tw[2 * t] = p0 / wsum;
    tw[2 * t + 1] = p1 / wsum;
    atomicAdd(&icnt[i0], 1);
    atomicAdd(&icnt[i1], 1);
    atomicAdd(&counts_out[i0], 1.0f);
    atomicAdd(&counts_out[i1], 1.0f);
  }
}

__global__ void init_kernel(float* __restrict__ counts_out, int* __restrict__ icnt,
                            int* __restrict__ cursor) {
  int i = threadIdx.x;
  if (i < NEXP) {
    counts_out[i] = 0.f;
    icnt[i] = 0;
    cursor[i] = 0;
  }
}

__global__ void scan_kernel(const int* __restrict__ icnt, int* __restrict__ ebase) {
  if (threadIdx.x == 0) {
    int s = 0;
    for (int e = 0; e < NEXP; ++e) {
      ebase[e] = s;
      s += icnt[e];
    }
  }
}

__global__ __launch_bounds__(256)
void scatter_kernel(const int* __restrict__ ti, const int* __restrict__ ebase,
                    int* __restrict__ cursor, int* __restrict__ tok2e) {
  int t = blockIdx.x * 256 + threadIdx.x;
#pragma unroll
  for (int s = 0; s < 2; ++s) {
    int e = ti[2 * t + s];
    int pos = atomicAdd(&cursor[e], 1);
    tok2e[ebase[e] + pos] = 2 * t + s;
  }
}

// out = x1 + tw0*y[2t] + tw1*y[2t+1]   (y in bf16)
__global__ __launch_bounds__(256)
void combine_kernel(const float* __restrict__ x1, const unsigned short* __restrict__ y,
                    const float* __restrict__ tw, float* __restrict__ out) {
  int idx = blockIdx.x * 256 + threadIdx.x;
  int t = idx >> 8, c = idx & 255;
  float w0 = tw[2 * t], w1 = tw[2 * t + 1];
  float4 a = ((const float4*)x1)[idx];
  const unsigned short* y0 = y + (size_t)(2 * t) * DMODEL + c * 4;
  const unsigned short* y1 = y0 + DMODEL;
  ushort4 u0 = *(const ushort4*)y0;
  ushort4 u1 = *(const ushort4*)y1;
  float4 o;
  o.x = a.x + w0 * bf2f(u0.x) + w1 * bf2f(u1.x);
  o.y = a.y + w0 * bf2f(u0.y) + w1 * bf2f(u1.y);
  o.z = a.z + w0 * bf2f(u0.z) + w1 * bf2f(u1.z);
  o.w = a.w + w0 * bf2f(u0.w) + w1 * bf2f(u1.w);
  ((float4*)out)[idx] = o;
}

// ----------------------------------------------------------------
extern "C" void kernel_launch(void* const* d_in, const int* in_sizes, int n_in,
                              void* d_out, int out_size, void* d_ws, size_t ws_size,
                              hipStream_t stream) {
  (void)in_sizes; (void)n_in; (void)ws_size;
  const float* x = (const float*)d_in[0];
  const float* tsq = (const float*)d_in[1];
  const float* tskv = (const float*)d_in[2];
  const float* attn_nw = (const float*)d_in[3];
  const float* ffn_nw = (const float*)d_in[4];
  const float* w_kv_c = (const float*)d_in[5];
  const float* w_kc_up = (const float*)d_in[6];
  const float* w_vc_up = (const float*)d_in[7];
  const float* w_qr = (const float*)d_in[8];
  const float* w_kr = (const float*)d_in[9];
  const float* w_o = (const float*)d_in[10];
  const float* gate_w = (const float*)d_in[11];
  const float* expert_bias = (const float*)d_in[12];
  const float* w1 = (const float*)d_in[13];
  const float* w2 = (const float*)d_in[14];

  float* out = (float*)d_out;
  float* counts_out = out + (out_size - NEXP);

  char* ws = (char*)d_ws;
  size_t off = 0;
  auto alloc = [&](size_t bytes) {
    char* p = ws + off;
    off += (bytes + 255) & ~(size_t)255;
    return p;
  };
  // LAYOUT INVARIANT: qb..kcb must stay 64MB contiguous (wxb overlay for MoE bf16 weights).
  float* h   = (float*)alloc((size_t)NTOK * DMODEL * 4);   // h, later x1
  float* qb  = (float*)alloc((size_t)NTOK * DMODEL * 4);   // q_r, later hn f32; wxb overlay base
  float* kb  = (float*)alloc((size_t)NTOK * DMODEL * 4);   // k_r
  float* vb  = (float*)alloc((size_t)NTOK * DMODEL * 4);   // 16MB slot; first 8MB = bf16 v_c (vbb)
  float* kcb = (float*)alloc((size_t)NTOK * DMODEL * 4);   // k_c
  unsigned short* yb  = (unsigned short*)alloc((size_t)NTOK * 2 * DMODEL * 2);  // bf16 y
  unsigned short* hb  = (unsigned short*)alloc((size_t)NTOK * DMODEL * 2);      // bf16 h / hn
  unsigned short* hmid = (unsigned short*)alloc((size_t)NTOK * 2 * DFF2 * 2);   // bf16, 64MB (attn overlay)
  unsigned short* ckvb = (unsigned short*)alloc((size_t)NTOK * DC * 2);         // bf16 ckv
  unsigned short* wbuf = (unsigned short*)alloc((size_t)2176 * DMODEL * 2);     // bf16 concat weight staging
  float* tw  = (float*)alloc((size_t)NTOK * 2 * 4);
  int* ti    = (int*)alloc((size_t)NTOK * 2 * 4);
  int* tok2e = (int*)alloc((size_t)NTOK * 2 * 4);
  int* icnt  = (int*)alloc(NEXP * 4);
  int* ebase = (int*)alloc(NEXP * 4);
  int* cursor = (int*)alloc(NEXP * 4);

  unsigned short* vbb = (unsigned short*)vb;  // bf16 v_c inside the vb slot
  // attention buffers overlay hmid (dead until moe FFN1): 4×8MB
  unsigned short* Qb = hmid;
  unsigned short* Kb = hmid + (size_t)4 * 1024 * 1024;
  unsigned short* Vt = hmid + (size_t)8 * 1024 * 1024;
  unsigned short* ao = hmid + (size_t)12 * 1024 * 1024;
  // MoE weight overlay on qb..kcb (64MB contiguous, all dead after gate/rope/v_split)
  unsigned short* wxb = (unsigned short*)qb;

  init_kernel<<<1, 64, 0, stream>>>(counts_out, icnt, cursor);
  rmsnorm_kernel<<<NTOK, 256, 0, stream>>>(x, attn_nw, nullptr, hb);
  // merged projection 1: [q_r | k_r | c_kv(bf16)] = h @ [w_qr; w_kr; w_kv_c]^T   (N = 2176)
  cvt3_bf16_kernel<<<1024, 256, 0, stream>>>(w_qr, DMODEL * DMODEL / 8,
                                             w_kr, DMODEL * DMODEL / 8,
                                             w_kv_c, DC * DMODEL / 8, wbuf);
  gemm_proj<<<dim3(17, 32), 256, 0, stream>>>(hb, wbuf, qb, kb, nullptr, nullptr, ckvb,
                                              1024, 2048, DMODEL, DMODEL, DC, DMODEL);
  // merged projection 2: [k_c | v_c(bf16)] = c_kv @ [w_kc_up; w_vc_up]^T   (N = 2048, K = 128)
  cvt3_bf16_kernel<<<64, 256, 0, stream>>>(w_kc_up, DMODEL * DC / 8,
                                           w_vc_up, DMODEL * DC / 8,
                                           w_vc_up, 0, wbuf);
  gemm_proj<<<dim3(16, 32), 256, 0, stream>>>(ckvb, wbuf, kcb, nullptr, nullptr, vbb, nullptr,
                                              1024, 2048, DMODEL, DMODEL, DMODEL, DC);
  // fused rope + ksum + bf16 relayout
  rope_qk_kernel<<<NTOK, 256, 0, stream>>>(qb, kb, kcb, tsq, tskv, Qb, Kb);
  v_split_kernel<<<dim3(64, 8), 256, 0, stream>>>(vbb, Vt);
  attn_mfma<<<dim3(8, 64), 256, 0, stream>>>(Qb, Kb, Vt, ao);
  // x1 = attn_out @ w_o^T + x
  cvt_bf16_kernel<<<512, 256, 0, stream>>>(w_o, wbuf, DMODEL * DMODEL / 8);
  gemm_bf16<<<dim3(8, 32), 256, 0, stream>>>(ao, wbuf, h, x, DMODEL, DMODEL);
  // FFN norm + gate + route (f32 exact gate path)
  rmsnorm_kernel<<<NTOK, 256, 0, stream>>>(h, ffn_nw, qb, hb);  // qb = hn f32, hb = hn bf16
  gate_kernel<<<NTOK / 4, 256, 0, stream>>>(qb, gate_w, expert_bias, ti, tw, icnt, counts_out);
  scan_kernel<<<1, 64, 0, stream>>>(icnt, ebase);
  scatter_kernel<<<NTOK / 256, 256, 0, stream>>>(ti, ebase, cursor, tok2e);
  // MoE (R7-exact bf16 kernel — best of 6 measured structures; MoE closed)
  cvt_bf16_kernel<<<2048, 256, 0, stream>>>(w1, wxb, NEXP * DFF2 * DMODEL / 8);
  moe_mfma<0><<<dim3(DFF2 / 128, NTOK / 128, NEXP), 256, 0, stream>>>(hb, wxb, hmid, tok2e, ebase, icnt);
  cvt_bf16_kernel<<<2048, 256, 0, stream>>>(w2, wxb, NEXP * DMODEL * DFF2 / 8);
  moe_mfma<1><<<dim3(DMODEL / 128, NTOK / 128, NEXP), 256, 0, stream>>>(hmid, wxb, yb, tok2e, ebase, icnt);
  combine_kernel<<<NTOK, 256, 0, stream>>>(h, yb, tw, out);
}

// Round 15
// 737.128 us; speedup vs baseline: 1.1613x; 1.0300x over previous
//
#include <hip/hip_runtime.h>
#include <hip/hip_bf16.h>

typedef __hip_bfloat16 bf16;
typedef __attribute__((ext_vector_type(8))) unsigned short ushort8v;
typedef __bf16 bf16x8 __attribute__((ext_vector_type(8)));
typedef float f32x4 __attribute__((ext_vector_type(4)));

#define NTOK 4096
#define DMODEL 1024
#define NHEADS 16
#define HD 64
#define DC 128
#define DFF2 4096
#define NEXP 8
#define LSEQ 1024
#define NBATCH 4
#define RMS_EPS 1.1920928955078125e-07f

union U8 { ushort8v u; bf16x8 b; };

__device__ __forceinline__ float bf2f(unsigned short u) {
  return __uint_as_float(((unsigned int)u) << 16);
}
__device__ __forceinline__ unsigned short f2bf(float f) {
  unsigned int u = __float_as_uint(f);
  unsigned int r = (u + 0x7FFF + ((u >> 16) & 1)) >> 16;
  return (unsigned short)r;
}
__device__ __forceinline__ void gload_lds16(const unsigned short* g, unsigned short* l) {
  __builtin_amdgcn_global_load_lds(
      (__attribute__((address_space(1))) void*)(const_cast<unsigned short*>(g)),
      (__attribute__((address_space(3))) void*)(l), 16, 0, 0);
}

// ---------------------------------------------------------------- rmsnorm (bf16 out)
__global__ __launch_bounds__(256)
void rmsnorm_kernel(const float* __restrict__ x, const float* __restrict__ w,
                    unsigned short* __restrict__ ob) {
  int t = blockIdx.x;
  int tid = threadIdx.x;
  const float4* xr = (const float4*)(x + (size_t)t * DMODEL);
  float4 v = xr[tid];
  float ss = v.x * v.x + v.y * v.y + v.z * v.z + v.w * v.w;
#pragma unroll
  for (int off = 32; off > 0; off >>= 1) ss += __shfl_xor(ss, off);
  __shared__ float red[4];
  int wid = tid >> 6, lane = tid & 63;
  if (lane == 0) red[wid] = ss;
  __syncthreads();
  float tot = red[0] + red[1] + red[2] + red[3];
  float scale = rsqrtf(tot * (1.0f / DMODEL) + RMS_EPS);
  float4 wv = ((const float4*)w)[tid];
  unsigned short* orow = ob + (size_t)t * DMODEL + tid * 4;
  orow[0] = f2bf(v.x * scale * wv.x);
  orow[1] = f2bf(v.y * scale * wv.y);
  orow[2] = f2bf(v.z * scale * wv.z);
  orow[3] = f2bf(v.w * scale * wv.w);
}

// ---------------------------------------------------------------- fused FFN rmsnorm + gate (f32-exact logits) + bf16 hn out
__global__ __launch_bounds__(256)
void rmsnorm_gate_kernel(const float* __restrict__ x, const float* __restrict__ w,
                         unsigned short* __restrict__ ob,
                         const float* __restrict__ gw, const float* __restrict__ bias,
                         int* __restrict__ ti, float* __restrict__ tw,
                         int* __restrict__ icnt, float* __restrict__ counts_out) {
  int t = blockIdx.x;
  int tid = threadIdx.x;
  const float4* xr = (const float4*)(x + (size_t)t * DMODEL);
  float4 v = xr[tid];
  float ss = v.x * v.x + v.y * v.y + v.z * v.z + v.w * v.w;
#pragma unroll
  for (int off = 32; off > 0; off >>= 1) ss += __shfl_xor(ss, off);
  __shared__ float red[4];
  __shared__ float red2[4][NEXP];
  int wid = tid >> 6, lane = tid & 63;
  if (lane == 0) red[wid] = ss;
  __syncthreads();
  float tot = red[0] + red[1] + red[2] + red[3];
  float scale = rsqrtf(tot * (1.0f / DMODEL) + RMS_EPS);
  float4 wv = ((const float4*)w)[tid];
  float4 ov;
  ov.x = v.x * scale * wv.x;
  ov.y = v.y * scale * wv.y;
  ov.z = v.z * scale * wv.z;
  ov.w = v.w * scale * wv.w;
  unsigned short* orow = ob + (size_t)t * DMODEL + tid * 4;
  orow[0] = f2bf(ov.x); orow[1] = f2bf(ov.y);
  orow[2] = f2bf(ov.z); orow[3] = f2bf(ov.w);
  // gate logits: partial[e] = dot(ov, gw[e][tid*4..+3]), block-reduced in f32
  float partial[NEXP];
#pragma unroll
  for (int e = 0; e < NEXP; ++e) {
    float4 g = ((const float4*)gw)[e * 256 + tid];
    partial[e] = ov.x * g.x + ov.y * g.y + ov.z * g.z + ov.w * g.w;
  }
#pragma unroll
  for (int e = 0; e < NEXP; ++e)
#pragma unroll
    for (int off = 32; off > 0; off >>= 1) partial[e] += __shfl_xor(partial[e], off);
  if (lane == 0)
#pragma unroll
    for (int e = 0; e < NEXP; ++e) red2[wid][e] = partial[e];
  __syncthreads();
  if (tid == 0) {
    float lg[NEXP], ex[NEXP];
    float mx = -1e30f;
#pragma unroll
    for (int e = 0; e < NEXP; ++e) {
      lg[e] = red2[0][e] + red2[1][e] + red2[2][e] + red2[3][e] + bias[e];
      mx = fmaxf(mx, lg[e]);
    }
#pragma unroll
    for (int e = 0; e < NEXP; ++e) ex[e] = expf(lg[e] - mx);
    int i0 = 0;
    float p0 = ex[0];
#pragma unroll
    for (int e = 1; e < NEXP; ++e)
      if (ex[e] > p0) { p0 = ex[e]; i0 = e; }
    int i1 = -1;
    float p1 = -1.f;
#pragma unroll
    for (int e = 0; e < NEXP; ++e)
      if (e != i0 && ex[e] > p1) { p1 = ex[e]; i1 = e; }
    float wsum = p0 + p1;
    ti[2 * t] = i0;
    ti[2 * t + 1] = i1;
    tw[2 * t] = p0 / wsum;
    tw[2 * t + 1] = p1 / wsum;
    atomicAdd(&icnt[i0], 1);
    atomicAdd(&icnt[i1], 1);
    atomicAdd(&counts_out[i0], 1.0f);
    atomicAdd(&counts_out[i1], 1.0f);
  }
}

// ---------------------------------------------------------------- f32 -> bf16 conversion (single src)
__global__ __launch_bounds__(256)
void cvt_bf16_kernel(const float* __restrict__ in, unsigned short* __restrict__ o, int n8) {
  int stride = gridDim.x * 256;
  for (int i = blockIdx.x * 256 + threadIdx.x; i < n8; i += stride) {
    float4 a = ((const float4*)in)[2 * i];
    float4 b = ((const float4*)in)[2 * i + 1];
    ushort8v u;
    u[0] = f2bf(a.x); u[1] = f2bf(a.y); u[2] = f2bf(a.z); u[3] = f2bf(a.w);
    u[4] = f2bf(b.x); u[5] = f2bf(b.y); u[6] = f2bf(b.z); u[7] = f2bf(b.w);
    *(ushort8v*)(o + (size_t)i * 8) = u;
  }
}

// ---------------------------------------------------------------- segmented f32 -> bf16 (up to 3 srcs, concat dst)
__global__ __launch_bounds__(256)
void cvt3_bf16_kernel(const float* __restrict__ s0, int n0,
                      const float* __restrict__ s1, int n1,
                      const float* __restrict__ s2, int n2,
                      unsigned short* __restrict__ o) {
  int total = n0 + n1 + n2;
  int stride = gridDim.x * 256;
  for (int i = blockIdx.x * 256 + threadIdx.x; i < total; i += stride) {
    const float* src;
    int li = i;
    if (li < n0) src = s0;
    else if ((li -= n0) < n1) src = s1;
    else { li -= n1; src = s2; }
    float4 a = ((const float4*)src)[2 * li];
    float4 b = ((const float4*)src)[2 * li + 1];
    ushort8v u;
    u[0] = f2bf(a.x); u[1] = f2bf(a.y); u[2] = f2bf(a.z); u[3] = f2bf(a.w);
    u[4] = f2bf(b.x); u[5] = f2bf(b.y); u[6] = f2bf(b.z); u[7] = f2bf(b.w);
    *(ushort8v*)(o + (size_t)i * 8) = u;
  }
}

// ---------------------------------------------------------------- dense bf16 MFMA GEMM, 64x128 tile (2 blocks/CU), + addend
// Same per-element K-accumulation order as the 128x128 kernel -> bitwise-identical C.
__global__ __launch_bounds__(256)
void gemm_bf16_64(const unsigned short* __restrict__ Ab, const unsigned short* __restrict__ Wb,
                  float* __restrict__ Cf, const float* __restrict__ addend, int N, int K) {
  __shared__ __align__(16) unsigned short As[64 * 64];    // 8 KB
  __shared__ __align__(16) unsigned short Bs[128 * 64];   // 16 KB
  int row0 = blockIdx.y * 64;
  int col0 = blockIdx.x * 128;
  int tid = threadIdx.x;
  int w = tid >> 6, l = tid & 63;
  int lr = l >> 3;
  int lc = (l & 7) * 8;

  const unsigned short* aSrc[2];
  const unsigned short* bSrc[4];
#pragma unroll
  for (int i = 0; i < 2; ++i)
    aSrc[i] = Ab + (size_t)(row0 + i * 32 + w * 8 + lr) * K + lc;
#pragma unroll
  for (int i = 0; i < 4; ++i)
    bSrc[i] = Wb + (size_t)(col0 + i * 32 + w * 8 + lr) * K + lc;

  f32x4 acc[4][2] = {};
  int ln = l & 15, lq = l >> 4;

  for (int k0 = 0; k0 < K; k0 += 64) {
#pragma unroll
    for (int i = 0; i < 2; ++i) gload_lds16(aSrc[i] + k0, &As[(i * 4 + w) * 512]);
#pragma unroll
    for (int i = 0; i < 4; ++i) gload_lds16(bSrc[i] + k0, &Bs[(i * 4 + w) * 512]);
    __syncthreads();
#pragma unroll
    for (int kk = 0; kk < 2; ++kk) {
      bf16x8 af[4], bfr[2];
#pragma unroll
      for (int m = 0; m < 4; ++m)
        af[m] = *(const bf16x8*)&As[(m * 16 + ln) * 64 + kk * 32 + lq * 8];
#pragma unroll
      for (int n = 0; n < 2; ++n)
        bfr[n] = *(const bf16x8*)&Bs[(w * 32 + n * 16 + ln) * 64 + kk * 32 + lq * 8];
#pragma unroll
      for (int m = 0; m < 4; ++m)
#pragma unroll
        for (int n = 0; n < 2; ++n)
          acc[m][n] = __builtin_amdgcn_mfma_f32_16x16x32_bf16(af[m], bfr[n], acc[m][n], 0, 0, 0);
    }
    __syncthreads();
  }

#pragma unroll
  for (int m = 0; m < 4; ++m) {
#pragma unroll
    for (int j = 0; j < 4; ++j) {
      int row = row0 + m * 16 + lq * 4 + j;
      size_t cidx = (size_t)row * N + col0 + w * 32 + ln;
      float* crow = Cf + cidx;
      const float* arow = addend ? addend + cidx : nullptr;
#pragma unroll
      for (int n = 0; n < 2; ++n) {
        float vv = acc[m][n][j];
        if (addend) vv += arow[n * 16];
        crow[n * 16] = vv;
      }
    }
  }
}

// ---------------------------------------------------------------- merged-projection GEMM (3-way dest epilogue)
// segment 1 [c1,c2) optionally bf16 via d1b; segment 2 [c2,..) optionally bf16 via d2b.
__global__ __launch_bounds__(256)
void gemm_proj(const unsigned short* __restrict__ Ab, const unsigned short* __restrict__ Wcat,
               float* __restrict__ d0, float* __restrict__ d1, float* __restrict__ d2,
               unsigned short* __restrict__ d1b, unsigned short* __restrict__ d2b,
               int c1, int c2, int s0, int s1, int s2, int K) {
  __shared__ __align__(16) unsigned short As[128 * 64];
  __shared__ __align__(16) unsigned short Bs[128 * 64];
  int row0 = blockIdx.y * 128;
  int col0 = blockIdx.x * 128;
  int tid = threadIdx.x;
  int w = tid >> 6, l = tid & 63;
  int lr = l >> 3;
  int lc = (l & 7) * 8;

  const unsigned short* aSrc[4];
  const unsigned short* bSrc[4];
#pragma unroll
  for (int i = 0; i < 4; ++i) {
    aSrc[i] = Ab + (size_t)(row0 + i * 32 + w * 8 + lr) * K + lc;
    bSrc[i] = Wcat + (size_t)(col0 + i * 32 + w * 8 + lr) * K + lc;
  }

  f32x4 acc[4][4] = {};
  int wr = w >> 1, wc = w & 1;
  int ln = l & 15, lq = l >> 4;

  for (int k0 = 0; k0 < K; k0 += 64) {
#pragma unroll
    for (int i = 0; i < 4; ++i) {
      gload_lds16(aSrc[i] + k0, &As[(i * 4 + w) * 512]);
      gload_lds16(bSrc[i] + k0, &Bs[(i * 4 + w) * 512]);
    }
    __syncthreads();
#pragma unroll
    for (int kk = 0; kk < 2; ++kk) {
      bf16x8 af[4], bfr[4];
#pragma unroll
      for (int m = 0; m < 4; ++m)
        af[m] = *(const bf16x8*)&As[(wr * 64 + m * 16 + ln) * 64 + kk * 32 + lq * 8];
#pragma unroll
      for (int n = 0; n < 4; ++n)
        bfr[n] = *(const bf16x8*)&Bs[(wc * 64 + n * 16 + ln) * 64 + kk * 32 + lq * 8];
#pragma unroll
      for (int m = 0; m < 4; ++m)
#pragma unroll
        for (int n = 0; n < 4; ++n)
          acc[m][n] = __builtin_amdgcn_mfma_f32_16x16x32_bf16(af[m], bfr[n], acc[m][n], 0, 0, 0);
    }
    __syncthreads();
  }

  bool seg1 = (col0 >= c1) && (col0 < c2);
  bool seg2 = (col0 >= c2);
  unsigned short* dbf = (seg1 && d1b) ? d1b : (seg2 && d2b) ? d2b : nullptr;
  if (dbf) {
    int cb = seg1 ? c1 : c2;
    int stride = seg1 ? s1 : s2;
#pragma unroll
    for (int m = 0; m < 4; ++m) {
#pragma unroll
      for (int j = 0; j < 4; ++j) {
        int row = row0 + wr * 64 + m * 16 + lq * 4 + j;
        unsigned short* crow = dbf + (size_t)row * stride + (col0 - cb) + wc * 64 + ln;
#pragma unroll
        for (int n = 0; n < 4; ++n) crow[n * 16] = f2bf(acc[m][n][j]);
      }
    }
    return;
  }
  float* dst;
  int cb, stride;
  if (col0 < c1) { dst = d0; cb = 0; stride = s0; }
  else if (seg1) { dst = d1; cb = c1; stride = s1; }
  else { dst = d2; cb = c2; stride = s2; }
#pragma unroll
  for (int m = 0; m < 4; ++m) {
#pragma unroll
    for (int j = 0; j < 4; ++j) {
      int row = row0 + wr * 64 + m * 16 + lq * 4 + j;
      float* crow = dst + (size_t)row * stride + (col0 - cb) + wc * 64 + ln;
#pragma unroll
      for (int n = 0; n < 4; ++n) crow[n * 16] = acc[m][n][j];
    }
  }
}

// ---------------------------------------------------------------- bf16 MFMA grouped GEMM (MoE), 128x128 — R7-exact (best of 6 measured)
template <int MODE>
__global__ __launch_bounds__(256)
void moe_mfma(const unsigned short* __restrict__ A, const unsigned short* __restrict__ Wb,
              unsigned short* __restrict__ Cout, const int* __restrict__ tok2e,
              const int* __restrict__ ebase, const int* __restrict__ icnt) {
  constexpr int N = (MODE == 0) ? DFF2 : DMODEL;
  constexpr int K = (MODE == 0) ? DMODEL : DFF2;
  __shared__ __align__(16) unsigned short As[128 * 64];
  __shared__ __align__(16) unsigned short Bs[128 * 64];
  int e = blockIdx.z;
  int base = ebase[e];
  int cnt = icnt[e];
  int row0 = blockIdx.y * 128;
  if (row0 >= cnt) return;
  int col0 = blockIdx.x * 128;
  int tid = threadIdx.x;
  int w = tid >> 6, l = tid & 63;
  int lr = l >> 3;
  int lc = (l & 7) * 8;

  const unsigned short* aSrc[4];
  const unsigned short* bSrc[4];
#pragma unroll
  for (int i = 0; i < 4; ++i) {
    int r = row0 + i * 32 + w * 8 + lr;
    r = r < cnt ? r : cnt - 1;
    if (MODE == 0) {
      int tok = tok2e[base + r] >> 1;
      aSrc[i] = A + (size_t)tok * K + lc;
    } else {
      aSrc[i] = A + (size_t)(base + r) * K + lc;
    }
    int nrow = col0 + i * 32 + w * 8 + lr;
    bSrc[i] = Wb + (size_t)e * N * K + (size_t)nrow * K + lc;
  }

  f32x4 acc[4][4] = {};
  int wr = w >> 1, wc = w & 1;
  int ln16 = l & 15, lq = l >> 4;

  for (int k0 = 0; k0 < K; k0 += 64) {
#pragma unroll
    for (int i = 0; i < 4; ++i) {
      gload_lds16(aSrc[i] + k0, &As[(i * 4 + w) * 512]);
      gload_lds16(bSrc[i] + k0, &Bs[(i * 4 + w) * 512]);
    }
    __syncthreads();
#pragma unroll
    for (int kk = 0; kk < 2; ++kk) {
      bf16x8 af[4], bfr[4];
#pragma unroll
      for (int m = 0; m < 4; ++m)
        af[m] = *(const bf16x8*)&As[(wr * 64 + m * 16 + ln16) * 64 + kk * 32 + lq * 8];
#pragma unroll
      for (int n = 0; n < 4; ++n)
        bfr[n] = *(const bf16x8*)&Bs[(wc * 64 + n * 16 + ln16) * 64 + kk * 32 + lq * 8];
#pragma unroll
      for (int m = 0; m < 4; ++m)
#pragma unroll
        for (int n = 0; n < 4; ++n)
          acc[m][n] = __builtin_amdgcn_mfma_f32_16x16x32_bf16(af[m], bfr[n], acc[m][n], 0, 0, 0);
    }
    __syncthreads();
  }

#pragma unroll
  for (int m = 0; m < 4; ++m) {
#pragma unroll
    for (int j = 0; j < 4; ++j) {
      int r = row0 + wr * 64 + m * 16 + lq * 4 + j;
      if (r < cnt) {
        if (MODE == 0) {
          unsigned short* orow = Cout + (size_t)(base + r) * N + col0 + wc * 64 + ln16;
#pragma unroll
          for (int n = 0; n < 4; ++n) {
            float v = acc[m][n][j];
            float s = v / (1.f + __expf(-v));
            orow[n * 16] = f2bf(s);
          }
        } else {
          int t2 = tok2e[base + r];
          unsigned short* orow = Cout + (size_t)t2 * N + col0 + wc * 64 + ln16;
#pragma unroll
          for (int n = 0; n < 4; ++n) orow[n * 16] = f2bf(acc[m][n][j]);
        }
      }
    }
  }
}

// ---------------------------------------------------------------- fused rope (cos-only) + ksum + bf16 per-(b,h) relayout
__global__ __launch_bounds__(256)
void rope_qk_kernel(const float* __restrict__ q, const float* __restrict__ k,
                    const float* __restrict__ kc, const float* __restrict__ tsq,
                    const float* __restrict__ tskv,
                    unsigned short* __restrict__ Qb, unsigned short* __restrict__ Kb) {
  int t = blockIdx.x;
  int tid = threadIdx.x;
  __shared__ float cq[32], ck[32];
  if (tid < 32) {
    float fr = __expf(-(float)(2 * tid) * (1.0f / HD) * 9.210340371976184f);  // ln(10000)
    cq[tid] = cosf(tsq[t] * fr);
    ck[tid] = cosf(tskv[t] * fr);
  }
  __syncthreads();
  int b = t >> 10, lrow = t & 1023;
  size_t rb = (size_t)t * DMODEL;
  for (int p = tid; p < 512; p += 256) {
    int hh = p >> 5, d = p & 31;
    int c1 = hh * 64 + d, c2 = c1 + 32;
    float cqd = cq[d], ckd = ck[d];
    float q1 = q[rb + c1], q2 = q[rb + c2];
    float rq1 = (q1 * cqd - q2 * ckd) * 0.125f;
    float rq2 = (q2 * cqd + q1 * ckd) * 0.125f;
    float k1 = k[rb + c1], k2 = k[rb + c2];
    float rk1 = (k1 * cqd - k2 * ckd) + kc[rb + c1];
    float rk2 = (k2 * cqd + k1 * ckd) + kc[rb + c2];
    size_t dst = ((size_t)(b * NHEADS + hh) * LSEQ + lrow) * HD;
    Qb[dst + d] = f2bf(rq1);
    Qb[dst + d + 32] = f2bf(rq2);
    Kb[dst + d] = f2bf(rk1);
    Kb[dst + d + 32] = f2bf(rk2);
  }
}

// ---------------------------------------------------------------- v transpose (bf16 in, bf16 out)  [bh][64][1024]
__global__ __launch_bounds__(256)
void v_split_kernel(const unsigned short* __restrict__ vbb, unsigned short* __restrict__ Vt) {
  __shared__ unsigned short tile[128][72];
  int bh = blockIdx.x;
  int lt = blockIdx.y;
  int b = bh >> 4, hh = bh & 15;
  int tid = threadIdx.x;
#pragma unroll
  for (int pass = 0; pass < 8; ++pass) {
    int r = pass * 16 + (tid >> 4);
    int dq = (tid & 15) * 4;
    ushort4 vv = *(const ushort4*)(vbb + (size_t)(b * 1024 + lt * 128 + r) * DMODEL + hh * 64 + dq);
    tile[r][dq + 0] = vv.x; tile[r][dq + 1] = vv.y;
    tile[r][dq + 2] = vv.z; tile[r][dq + 3] = vv.w;
  }
  __syncthreads();
  int d = tid >> 2, seg = (tid & 3) * 32;
  size_t obase = ((size_t)bh * HD + d) * LSEQ + lt * 128 + seg;
  for (int i = 0; i < 32; i += 4) {
    ushort4 u;
    u.x = tile[seg + i][d];
    u.y = tile[seg + i + 1][d];
    u.z = tile[seg + i + 2][d];
    u.w = tile[seg + i + 3][d];
    *(ushort4*)(Vt + obase + i) = u;
  }
}

// ---------------------------------------------------------------- bf16 MFMA flash attention
__global__ __launch_bounds__(256, 2)
void attn_mfma(const unsigned short* __restrict__ Qb, const unsigned short* __restrict__ Kb,
               const unsigned short* __restrict__ Vt, unsigned short* __restrict__ ao) {
  __shared__ unsigned int plds[128 * 128];  // P in hi 16 bits, 32B-XOR swizzled
  int bh = blockIdx.y;
  int qt = blockIdx.x;
  int tid = threadIdx.x;
  int w = tid >> 6, l = tid & 63;
  int ln = l & 15, lq = l >> 4;
  size_t kvbase = (size_t)bh * LSEQ * HD;
  int qrow0 = qt * 128 + w * 32;

  bf16x8 qh[2][2];
#pragma unroll
  for (int mi = 0; mi < 2; ++mi)
#pragma unroll
    for (int ks = 0; ks < 2; ++ks) {
      size_t o = kvbase + (size_t)(qrow0 + mi * 16 + ln) * HD + ks * 32 + lq * 8;
      qh[mi][ks] = *(const bf16x8*)(Qb + o);
    }

  float l_run[2][4] = {};
  f32x4 oacc[2][4] = {};

  for (int kt = 0; kt < 8; ++kt) {
    int k0 = kt * 128;
    f32x4 sacc[2][8] = {};
#pragma unroll
    for (int ni = 0; ni < 8; ++ni) {
      size_t ko = kvbase + (size_t)(k0 + ni * 16 + ln) * HD + lq * 8;
      bf16x8 kh0 = *(const bf16x8*)(Kb + ko);
      bf16x8 kh1 = *(const bf16x8*)(Kb + ko + 32);
#pragma unroll
      for (int mi = 0; mi < 2; ++mi) {
        f32x4 a = sacc[mi][ni];
        a = __builtin_amdgcn_mfma_f32_16x16x32_bf16(qh[mi][0], kh0, a, 0, 0, 0);
        a = __builtin_amdgcn_mfma_f32_16x16x32_bf16(qh[mi][1], kh1, a, 0, 0, 0);
        sacc[mi][ni] = a;
      }
    }
#pragma unroll
    for (int mi = 0; mi < 2; ++mi)
#pragma unroll
      for (int j = 0; j < 4; ++j) {
        float rs = 0.f;
#pragma unroll
        for (int ni = 0; ni < 8; ++ni) {
          float p = __expf(sacc[mi][ni][j]);
          sacc[mi][ni][j] = p;
          rs += p;
        }
        rs += __shfl_xor(rs, 1);
        rs += __shfl_xor(rs, 2);
        rs += __shfl_xor(rs, 4);
        rs += __shfl_xor(rs, 8);
        l_run[mi][j] += rs;
      }
#pragma unroll
    for (int mi = 0; mi < 2; ++mi)
#pragma unroll
      for (int ni = 0; ni < 8; ++ni)
#pragma unroll
        for (int j = 0; j < 4; ++j) {
          int row = w * 32 + mi * 16 + lq * 4 + j;
          int col = ni * 16 + ln;
          unsigned int u = ((unsigned int)f2bf(sacc[mi][ni][j])) << 16;
          plds[row * 128 + (col ^ ((row & 3) << 3))] = u;
        }
    __syncthreads();
#pragma unroll
    for (int ksp = 0; ksp < 4; ++ksp) {
      bf16x8 ph[2];
#pragma unroll
      for (int mi = 0; mi < 2; ++mi) {
        int row = w * 32 + mi * 16 + ln;
        int c0 = ksp * 32 + lq * 8;
        const unsigned int* pp = &plds[row * 128 + (c0 ^ ((row & 3) << 3))];
        uint4 u0 = *(const uint4*)pp;
        uint4 u1 = *(const uint4*)(pp + 4);
        unsigned int uu[8] = {u0.x, u0.y, u0.z, u0.w, u1.x, u1.y, u1.z, u1.w};
        U8 uh;
#pragma unroll
        for (int jj = 0; jj < 8; ++jj) uh.u[jj] = (unsigned short)(uu[jj] >> 16);
        ph[mi] = uh.b;
      }
#pragma unroll
      for (int ni = 0; ni < 4; ++ni) {
        size_t vo = kvbase + (size_t)(ni * 16 + ln) * LSEQ + k0 + ksp * 32 + lq * 8;
        bf16x8 vh = *(const bf16x8*)(Vt + vo);
#pragma unroll
        for (int mi = 0; mi < 2; ++mi)
          oacc[mi][ni] = __builtin_amdgcn_mfma_f32_16x16x32_bf16(ph[mi], vh, oacc[mi][ni], 0, 0, 0);
      }
    }
    __syncthreads();
  }

  int b = bh >> 4, hh = bh & 15;
#pragma unroll
  for (int mi = 0; mi < 2; ++mi) {
    float inv[4];
#pragma unroll
    for (int j = 0; j < 4; ++j) inv[j] = 1.0f / l_run[mi][j];
#pragma unroll
    for (int ni = 0; ni < 4; ++ni)
#pragma unroll
      for (int j = 0; j < 4; ++j) {
        int tok = b * 1024 + qt * 128 + w * 32 + mi * 16 + lq * 4 + j;
        int col = hh * 64 + ni * 16 + ln;
        ao[(size_t)tok * DMODEL + col] = f2bf(oacc[mi][ni][j] * inv[j]);
      }
  }
}

__global__ void init_kernel(float* __restrict__ counts_out, int* __restrict__ icnt,
                            int* __restrict__ cursor) {
  int i = threadIdx.x;
  if (i < NEXP) {
    counts_out[i] = 0.f;
    icnt[i] = 0;
    cursor[i] = 0;
  }
}

__global__ void scan_kernel(const int* __restrict__ icnt, int* __restrict__ ebase) {
  if (threadIdx.x == 0) {
    int s = 0;
    for (int e = 0; e < NEXP; ++e) {
      ebase[e] = s;
      s += icnt[e];
    }
  }
}

__global__ __launch_bounds__(256)
void scatter_kernel(const int* __restrict__ ti, const int* __restrict__ ebase,
                    int* __restrict__ cursor, int* __restrict__ tok2e) {
  int t = blockIdx.x * 256 + threadIdx.x;
#pragma unroll
  for (int s = 0; s < 2; ++s) {
    int e = ti[2 * t + s];
    int pos = atomicAdd(&cursor[e], 1);
    tok2e[ebase[e] + pos] = 2 * t + s;
  }
}

// out = x1 + tw0*y[2t] + tw1*y[2t+1]   (y in bf16)
__global__ __launch_bounds__(256)
void combine_kernel(const float* __restrict__ x1, const unsigned short* __restrict__ y,
                    const float* __restrict__ tw, float* __restrict__ out) {
  int idx = blockIdx.x * 256 + threadIdx.x;
  int t = idx >> 8, c = idx & 255;
  float w0 = tw[2 * t], w1 = tw[2 * t + 1];
  float4 a = ((const float4*)x1)[idx];
  const unsigned short* y0 = y + (size_t)(2 * t) * DMODEL + c * 4;
  const unsigned short* y1 = y0 + DMODEL;
  ushort4 u0 = *(const ushort4*)y0;
  ushort4 u1 = *(const ushort4*)y1;
  float4 o;
  o.x = a.x + w0 * bf2f(u0.x) + w1 * bf2f(u1.x);
  o.y = a.y + w0 * bf2f(u0.y) + w1 * bf2f(u1.y);
  o.z = a.z + w0 * bf2f(u0.z) + w1 * bf2f(u1.z);
  o.w = a.w + w0 * bf2f(u0.w) + w1 * bf2f(u1.w);
  ((float4*)out)[idx] = o;
}

// ----------------------------------------------------------------
extern "C" void kernel_launch(void* const* d_in, const int* in_sizes, int n_in,
                              void* d_out, int out_size, void* d_ws, size_t ws_size,
                              hipStream_t stream) {
  (void)in_sizes; (void)n_in; (void)ws_size;
  const float* x = (const float*)d_in[0];
  const float* tsq = (const float*)d_in[1];
  const float* tskv = (const float*)d_in[2];
  const float* attn_nw = (const float*)d_in[3];
  const float* ffn_nw = (const float*)d_in[4];
  const float* w_kv_c = (const float*)d_in[5];
  const float* w_kc_up = (const float*)d_in[6];
  const float* w_vc_up = (const float*)d_in[7];
  const float* w_qr = (const float*)d_in[8];
  const float* w_kr = (const float*)d_in[9];
  const float* w_o = (const float*)d_in[10];
  const float* gate_w = (const float*)d_in[11];
  const float* expert_bias = (const float*)d_in[12];
  const float* w1 = (const float*)d_in[13];
  const float* w2 = (const float*)d_in[14];

  float* out = (float*)d_out;
  float* counts_out = out + (out_size - NEXP);

  char* ws = (char*)d_ws;
  size_t off = 0;
  auto alloc = [&](size_t bytes) {
    char* p = ws + off;
    off += (bytes + 255) & ~(size_t)255;
    return p;
  };
  // LAYOUT INVARIANT: qb..kcb must stay 64MB contiguous (wxb overlay for MoE bf16 weights).
  float* h   = (float*)alloc((size_t)NTOK * DMODEL * 4);   // h, later x1
  float* qb  = (float*)alloc((size_t)NTOK * DMODEL * 4);   // q_r; wxb overlay base
  float* kb  = (float*)alloc((size_t)NTOK * DMODEL * 4);   // k_r
  float* vb  = (float*)alloc((size_t)NTOK * DMODEL * 4);   // 16MB slot; first 8MB = bf16 v_c (vbb)
  float* kcb = (float*)alloc((size_t)NTOK * DMODEL * 4);   // k_c
  unsigned short* yb  = (unsigned short*)alloc((size_t)NTOK * 2 * DMODEL * 2);  // bf16 y
  unsigned short* hb  = (unsigned short*)alloc((size_t)NTOK * DMODEL * 2);      // bf16 h / hn
  unsigned short* hmid = (unsigned short*)alloc((size_t)NTOK * 2 * DFF2 * 2);   // bf16, 64MB (attn overlay)
  unsigned short* ckvb = (unsigned short*)alloc((size_t)NTOK * DC * 2);         // bf16 ckv
  unsigned short* wbuf = (unsigned short*)alloc((size_t)2176 * DMODEL * 2);     // bf16 concat weight staging
  float* tw  = (float*)alloc((size_t)NTOK * 2 * 4);
  int* ti    = (int*)alloc((size_t)NTOK * 2 * 4);
  int* tok2e = (int*)alloc((size_t)NTOK * 2 * 4);
  int* icnt  = (int*)alloc(NEXP * 4);
  int* ebase = (int*)alloc(NEXP * 4);
  int* cursor = (int*)alloc(NEXP * 4);

  unsigned short* vbb = (unsigned short*)vb;  // bf16 v_c inside the vb slot
  // attention buffers overlay hmid (dead until moe FFN1): 4×8MB
  unsigned short* Qb = hmid;
  unsigned short* Kb = hmid + (size_t)4 * 1024 * 1024;
  unsigned short* Vt = hmid + (size_t)8 * 1024 * 1024;
  unsigned short* ao = hmid + (size_t)12 * 1024 * 1024;
  // MoE weight overlay on qb..kcb (64MB contiguous, all dead after routing)
  unsigned short* wxb = (unsigned short*)qb;

  init_kernel<<<1, 64, 0, stream>>>(counts_out, icnt, cursor);
  rmsnorm_kernel<<<NTOK, 256, 0, stream>>>(x, attn_nw, hb);
  // merged projection 1: [q_r | k_r | c_kv(bf16)] = h @ [w_qr; w_kr; w_kv_c]^T   (N = 2176)
  cvt3_bf16_kernel<<<1024, 256, 0, stream>>>(w_qr, DMODEL * DMODEL / 8,
                                             w_kr, DMODEL * DMODEL / 8,
                                             w_kv_c, DC * DMODEL / 8, wbuf);
  gemm_proj<<<dim3(17, 32), 256, 0, stream>>>(hb, wbuf, qb, kb, nullptr, nullptr, ckvb,
                                              1024, 2048, DMODEL, DMODEL, DC, DMODEL);
  // merged projection 2: [k_c | v_c(bf16)] = c_kv @ [w_kc_up; w_vc_up]^T   (N = 2048, K = 128)
  cvt3_bf16_kernel<<<64, 256, 0, stream>>>(w_kc_up, DMODEL * DC / 8,
                                           w_vc_up, DMODEL * DC / 8,
                                           w_vc_up, 0, wbuf);
  gemm_proj<<<dim3(16, 32), 256, 0, stream>>>(ckvb, wbuf, kcb, nullptr, nullptr, vbb, nullptr,
                                              1024, 2048, DMODEL, DMODEL, DMODEL, DC);
  // fused rope + ksum + bf16 relayout
  rope_qk_kernel<<<NTOK, 256, 0, stream>>>(qb, kb, kcb, tsq, tskv, Qb, Kb);
  v_split_kernel<<<dim3(64, 8), 256, 0, stream>>>(vbb, Vt);
  attn_mfma<<<dim3(8, 64), 256, 0, stream>>>(Qb, Kb, Vt, ao);
  // x1 = attn_out @ w_o^T + x   (64x128 tile, 512 blocks; bitwise == 128x128 version)
  cvt_bf16_kernel<<<512, 256, 0, stream>>>(w_o, wbuf, DMODEL * DMODEL / 8);
  gemm_bf16_64<<<dim3(8, 64), 256, 0, stream>>>(ao, wbuf, h, x, DMODEL, DMODEL);
  // fused FFN rmsnorm + gate (f32-exact logits) + routing
  rmsnorm_gate_kernel<<<NTOK, 256, 0, stream>>>(h, ffn_nw, hb, gate_w, expert_bias,
                                                ti, tw, icnt, counts_out);
  scan_kernel<<<1, 64, 0, stream>>>(icnt, ebase);
  scatter_kernel<<<NTOK / 256, 256, 0, stream>>>(ti, ebase, cursor, tok2e);
  // MoE (R7-exact bf16 kernel — best of 6 measured structures; MoE closed)
  cvt_bf16_kernel<<<2048, 256, 0, stream>>>(w1, wxb, NEXP * DFF2 * DMODEL / 8);
  moe_mfma<0><<<dim3(DFF2 / 128, NTOK / 128, NEXP), 256, 0, stream>>>(hb, wxb, hmid, tok2e, ebase, icnt);
  cvt_bf16_kernel<<<2048, 256, 0, stream>>>(w2, wxb, NEXP * DMODEL * DFF2 / 8);
  moe_mfma<1><<<dim3(DMODEL / 128, NTOK / 128, NEXP), 256, 0, stream>>>(hmid, wxb, yb, tok2e, ebase, icnt);
  combine_kernel<<<NTOK, 256, 0, stream>>>(h, yb, tw, out);
}